// Round 1
// baseline (8030.128 us; speedup 1.0000x reference)
//
#include <hip/hip_runtime.h>

#define LL 65536      // H*W
#define KSEL 655      // top-k count
#define CI_CHUNK 4

// ---------------------------------------------------------------------------
// Zero the 1-wide borders of two padded square buffers (C=256 planes each).
// ---------------------------------------------------------------------------
__global__ void zb_kernel(float* __restrict__ A, int H2a, float* __restrict__ B, int H2b)
{
  const int perA = 4*H2a - 4, perB = 4*H2b - 4;
  const int totA = 256*perA, tot = totA + 256*perB;
  for (int t = blockIdx.x*blockDim.x + threadIdx.x; t < tot; t += gridDim.x*blockDim.x) {
    float* buf; int H2, per, tt;
    if (t < totA) { buf = A; H2 = H2a; per = perA; tt = t; }
    else          { buf = B; H2 = H2b; per = perB; tt = t - totA; }
    int c = tt / per, j = tt - c*per;
    int y, x;
    if (j < H2)        { y = 0;      x = j; }
    else if (j < 2*H2) { y = H2-1;   x = j - H2; }
    else { int k2 = j - 2*H2; y = 1 + (k2 >> 1); x = (k2 & 1) ? (H2-1) : 0; }
    buf[c*H2*H2 + y*H2 + x] = 0.f;
  }
}

// ---------------------------------------------------------------------------
// 1x1 conv: swinT (768,8,8) -> out (256, 10,10) padded interior.
// grid: 256 blocks (co), block: 64 threads (pixel)
// ---------------------------------------------------------------------------
__global__ void __launch_bounds__(64) conv1x1_kernel(
    const float* __restrict__ swinT, const float* __restrict__ w,
    const float* __restrict__ b, float* __restrict__ out)
{
  const int co = blockIdx.x, pp = threadIdx.x;
  float acc = b[co];
  for (int ci = 0; ci < 768; ++ci)
    acc += swinT[ci*64 + pp] * w[co*768 + ci];
  const int py = pp >> 3, px = pp & 7;
  out[co*100 + (py+1)*10 + (px+1)] = acc;
}

// ---------------------------------------------------------------------------
// ConvTranspose2d k4 s2 p1 + ReLU.  Padded in (256,hi+2,wi+2) -> padded out.
// Decomposed by output parity: padded row = yi + py + dy, ky = 3 - py - 2*dy.
// block 256 = 16x16 threads, each owns a 2x2 output pixel quad, 8 co.
// grid: (ceil(wo/32), ceil(ho/32), 32)
// ---------------------------------------------------------------------------
__global__ void __launch_bounds__(256) convt_kernel(
    const float* __restrict__ in, const float* __restrict__ wt,
    const float* __restrict__ bias, float* __restrict__ out, int hi, int wi)
{
  const int ho = hi*2, wo = wi*2;
  const int Wi2 = wi+2, Wo2 = wo+2;
  const int planeI = (hi+2)*Wi2, planeO = (ho+2)*Wo2;
  const int tx = threadIdx.x & 15, ty = threadIdx.x >> 4;
  const int X0 = blockIdx.x*32, Y0 = blockIdx.y*32;
  const int Xi0 = X0 >> 1, Yi0 = Y0 >> 1;
  const int cb = blockIdx.z*8;

  __shared__ float tile[CI_CHUNK][18*18];
  float acc[8][2][2] = {};

  for (int c0 = 0; c0 < 256; c0 += CI_CHUNK) {
    for (int t = threadIdx.x; t < CI_CHUNK*324; t += 256) {
      int cc = t / 324, e = t - cc*324;
      int r = e / 18, s = e - r*18;
      int gr = Yi0 + r, gc = Xi0 + s;
      float v = 0.f;
      if (gr < hi+2 && gc < wi+2)
        v = in[(c0+cc)*planeI + gr*Wi2 + gc];
      tile[cc][e] = v;
    }
    __syncthreads();
    for (int cc = 0; cc < CI_CHUNK; ++cc) {
      const int ci = c0 + cc;
      float iv[3][3];
      #pragma unroll
      for (int r = 0; r < 3; ++r)
        #pragma unroll
        for (int s = 0; s < 3; ++s)
          iv[r][s] = tile[cc][(ty+r)*18 + (tx+s)];
      const float* wp = wt + (size_t)(ci*256 + cb)*16;
      #pragma unroll
      for (int j = 0; j < 8; ++j) {
        const float* w = wp + j*16;   // w[ky*4+kx]
        acc[j][0][0] += iv[0][0]*w[15] + iv[0][1]*w[13] + iv[1][0]*w[7]  + iv[1][1]*w[5];
        acc[j][0][1] += iv[0][1]*w[14] + iv[0][2]*w[12] + iv[1][1]*w[6]  + iv[1][2]*w[4];
        acc[j][1][0] += iv[1][0]*w[11] + iv[1][1]*w[9]  + iv[2][0]*w[3]  + iv[2][1]*w[1];
        acc[j][1][1] += iv[1][1]*w[10] + iv[1][2]*w[8]  + iv[2][1]*w[2]  + iv[2][2]*w[0];
      }
    }
    __syncthreads();
  }
  #pragma unroll
  for (int j = 0; j < 8; ++j) {
    const float bv = bias[cb+j];
    #pragma unroll
    for (int py = 0; py < 2; ++py)
      #pragma unroll
      for (int px = 0; px < 2; ++px) {
        int y = Y0 + 2*ty + py, x = X0 + 2*tx + px;
        if (y < ho && x < wo)
          out[(cb+j)*planeO + (y+1)*Wo2 + (x+1)] = fmaxf(acc[j][py][px] + bv, 0.f);
      }
  }
}

// ---------------------------------------------------------------------------
// Conv2d 3x3 pad1. Padded in -> padded out. block 256 = 16x16 px, 16 co each.
// grid: (w/16, h/16, 16)
// ---------------------------------------------------------------------------
__global__ void __launch_bounds__(256) conv3_kernel(
    const float* __restrict__ in, const float* __restrict__ wt,
    const float* __restrict__ bias, float* __restrict__ out, int h, int w)
{
  const int W2 = w+2, plane = (h+2)*W2;
  const int tx = threadIdx.x & 15, ty = threadIdx.x >> 4;
  const int X0 = blockIdx.x*16, Y0 = blockIdx.y*16;
  const int cb = blockIdx.z*16;

  __shared__ float tile[CI_CHUNK][18*18];
  float acc[16] = {};

  for (int c0 = 0; c0 < 256; c0 += CI_CHUNK) {
    for (int t = threadIdx.x; t < CI_CHUNK*324; t += 256) {
      int cc = t / 324, e = t - cc*324;
      int r = e / 18, s = e - r*18;
      int gr = Y0 + r, gc = X0 + s;
      float v = 0.f;
      if (gr < h+2 && gc < w+2)
        v = in[(c0+cc)*plane + gr*W2 + gc];
      tile[cc][e] = v;
    }
    __syncthreads();
    for (int cc = 0; cc < CI_CHUNK; ++cc) {
      const int ci = c0 + cc;
      float iv[9];
      #pragma unroll
      for (int r = 0; r < 3; ++r)
        #pragma unroll
        for (int s = 0; s < 3; ++s)
          iv[r*3+s] = tile[cc][(ty+r)*18 + (tx+s)];
      #pragma unroll
      for (int j = 0; j < 16; ++j) {
        const float* wp = wt + (size_t)((cb+j)*256 + ci)*9;
        acc[j] += iv[0]*wp[0] + iv[1]*wp[1] + iv[2]*wp[2]
                + iv[3]*wp[3] + iv[4]*wp[4] + iv[5]*wp[5]
                + iv[6]*wp[6] + iv[7]*wp[7] + iv[8]*wp[8];
      }
    }
    __syncthreads();
  }
  const int y = Y0 + ty, x = X0 + tx;
  if (y < h && x < w) {
    #pragma unroll
    for (int j = 0; j < 16; ++j)
      out[(cb+j)*plane + (y+1)*W2 + (x+1)] = acc[j] + bias[cb+j];
  }
}

// ---------------------------------------------------------------------------
// gate[l] = sigmoid(sum_c down[c*L+l]*gw[c] + gb)
// ---------------------------------------------------------------------------
__global__ void __launch_bounds__(256) gate_kernel(
    const float* __restrict__ down, const float* __restrict__ gw,
    const float* __restrict__ gb, float* __restrict__ gate)
{
  const int l = blockIdx.x*256 + threadIdx.x;
  float a0 = 0.f, a1 = 0.f, a2 = 0.f, a3 = 0.f;
  for (int c = 0; c < 256; c += 4) {
    a0 += down[(c+0)*LL + l] * gw[c+0];
    a1 += down[(c+1)*LL + l] * gw[c+1];
    a2 += down[(c+2)*LL + l] * gw[c+2];
    a3 += down[(c+3)*LL + l] * gw[c+3];
  }
  const float a = (a0+a1) + (a2+a3) + gb[0];
  gate[l] = 1.f / (1.f + expf(-a));
}

// ---------------------------------------------------------------------------
// Exact top-K selection (set semantics, ties -> lowest index), single block.
// gate in (0,1) => float bits are order-preserving unsigned ints.
// ---------------------------------------------------------------------------
__global__ void __launch_bounds__(1024) topk_kernel(
    const float* __restrict__ gate, int* __restrict__ sel)
{
  __shared__ unsigned hist[256];
  __shared__ unsigned s_pref;
  __shared__ int s_kk;
  __shared__ int wsum[16];
  __shared__ int s_base;
  const int tid = threadIdx.x;

  unsigned pref = 0; int kk = KSEL;
  for (int pass = 0; pass < 4; ++pass) {
    const int shift = 24 - 8*pass;
    if (tid < 256) hist[tid] = 0;
    __syncthreads();
    for (int i = tid; i < LL; i += 1024) {
      unsigned u = __float_as_uint(gate[i]);
      bool ok;
      if (pass == 0) ok = true;
      else           ok = ((u >> (shift + 8)) == pref);
      if (ok) atomicAdd(&hist[(u >> shift) & 255u], 1u);
    }
    __syncthreads();
    if (tid == 0) {
      int cum = 0, b = 255;
      for (; b >= 0; --b) {
        int c = (int)hist[b];
        if (cum + c >= kk) break;
        cum += c;
      }
      if (b < 0) b = 0;
      s_pref = (pref << 8) | (unsigned)b;
      s_kk = kk - cum;
    }
    __syncthreads();
    pref = s_pref; kk = s_kk;
    __syncthreads();
  }
  const unsigned T = pref;
  const int need = kk;                    // number of ==T entries to keep
  const int lane = tid & 63, wv = tid >> 6;

  // pass 1: indices with value > T, in ascending index order
  if (tid == 0) s_base = 0;
  __syncthreads();
  for (int i0 = 0; i0 < LL; i0 += 1024) {
    const unsigned u = __float_as_uint(gate[i0 + tid]);
    const bool f = (u > T);
    const unsigned long long m = __ballot(f);
    const int pre = __popcll(m & ((1ull << lane) - 1ull));
    if (lane == 0) wsum[wv] = __popcll(m);
    __syncthreads();
    if (tid == 0) {
      int s = s_base;
      for (int w = 0; w < 16; ++w) { int t = wsum[w]; wsum[w] = s; s += t; }
      s_base = s;
    }
    __syncthreads();
    if (f) sel[wsum[wv] + pre] = i0 + tid;
    __syncthreads();
  }
  const int cgt = s_base;
  __syncthreads();
  if (tid == 0) s_base = 0;
  __syncthreads();
  // pass 2: first `need` indices with value == T
  for (int i0 = 0; i0 < LL; i0 += 1024) {
    const unsigned u = __float_as_uint(gate[i0 + tid]);
    const bool f = (u == T);
    const unsigned long long m = __ballot(f);
    const int pre = __popcll(m & ((1ull << lane) - 1ull));
    if (lane == 0) wsum[wv] = __popcll(m);
    __syncthreads();
    if (tid == 0) {
      int s = s_base;
      for (int w = 0; w < 16; ++w) { int t = wsum[w]; wsum[w] = s; s += t; }
      s_base = s;
    }
    __syncthreads();
    const int pos = wsum[wv] + pre;
    if (f && pos < need) sel[cgt + pos] = i0 + tid;
    __syncthreads();
  }
}

// ---------------------------------------------------------------------------
// 32x32 LDS transpose: in (R, Ck) row-major -> out (Ck, R)
// ---------------------------------------------------------------------------
__global__ void __launch_bounds__(256) transpose_kernel(
    const float* __restrict__ in, float* __restrict__ out, int R, int Ck)
{
  __shared__ float t[32][33];
  const int bx = blockIdx.x*32, by = blockIdx.y*32;
  const int x = threadIdx.x & 31, y4 = threadIdx.x >> 5;
  #pragma unroll
  for (int i = 0; i < 4; ++i) {
    int r = by + y4 + i*8, c = bx + x;
    t[y4 + i*8][x] = (r < R && c < Ck) ? in[r*Ck + c] : 0.f;
  }
  __syncthreads();
  #pragma unroll
  for (int i = 0; i < 4; ++i) {
    int c = bx + y4 + i*8, r = by + x;
    if (c < Ck && r < R) out[c*R + r] = t[x][y4 + i*8];
  }
}

// ---------------------------------------------------------------------------
// Gather the selected rows from down (C,L) and padded x_final (C,258,258).
// ---------------------------------------------------------------------------
__global__ void __launch_bounds__(256) gather_kernel(
    const float* __restrict__ down, const float* __restrict__ xf,
    const int* __restrict__ sel, float* __restrict__ q_in, float* __restrict__ kv_in)
{
  const int n = blockIdx.x, c = threadIdx.x;
  const int l = sel[n];
  q_in[n*256 + c] = down[c*LL + l];
  const int pr = (l >> 8) + 1, pc = (l & 255) + 1;
  kv_in[n*256 + c] = xf[c*66564 + pr*258 + pc];
}

// ---------------------------------------------------------------------------
// out[n, co] = bias[co_base+tid] + sum_ci src[n,ci] * WT[ci, co_base+tid]
// grid (ceil(N/16), G); g==0 uses srcA else srcB; out offset g*KSEL*256.
// ---------------------------------------------------------------------------
__global__ void __launch_bounds__(256) rowgemm_kernel(
    const float* __restrict__ WT, int wld,
    const float* __restrict__ srcA, const float* __restrict__ srcB,
    const float* __restrict__ bias, float* __restrict__ out, int N)
{
  const int g = blockIdx.y;
  const int tid = threadIdx.x;
  const int co = g*256 + tid;
  const float* src = (g == 0) ? srcA : srcB;
  float* outg = out + (size_t)g*(KSEL*256);
  __shared__ float Bl[16][256];
  const int n0 = blockIdx.x*16;
  #pragma unroll
  for (int j = 0; j < 16; ++j) {
    int n = n0 + j;
    Bl[j][tid] = (n < N) ? src[n*256 + tid] : 0.f;
  }
  __syncthreads();
  float acc[16];
  const float bv = bias[co];
  #pragma unroll
  for (int j = 0; j < 16; ++j) acc[j] = bv;
  #pragma unroll 4
  for (int ci = 0; ci < 256; ++ci) {
    const float w = WT[ci*wld + co];
    #pragma unroll
    for (int j = 0; j < 16; ++j) acc[j] += Bl[j][ci]*w;
  }
  #pragma unroll
  for (int j = 0; j < 16; ++j) {
    int n = n0 + j;
    if (n < N) outg[n*256 + tid] = acc[j];
  }
}

// ---------------------------------------------------------------------------
// Attention per (n, h): scores -> softmax -> ctx. 655 keys.
// ---------------------------------------------------------------------------
__global__ void __launch_bounds__(256) attn_kernel(
    const float* __restrict__ qb, const float* __restrict__ kb,
    const float* __restrict__ vb, float* __restrict__ ctx)
{
  const int n = blockIdx.x, h = blockIdx.y;
  const int tid = threadIdx.x;
  __shared__ float sc[KSEL];
  __shared__ float qv[32];
  __shared__ float red[4];
  __shared__ float part[8][32];
  __shared__ float s_mx, s_sum;

  if (tid < 32) qv[tid] = qb[n*256 + h*32 + tid];
  __syncthreads();

  const float scale = 0.17677669529663687f;   // 1/sqrt(32)
  for (int m = tid; m < KSEL; m += 256) {
    const float* kr = kb + m*256 + h*32;
    float s = 0.f;
    #pragma unroll
    for (int d = 0; d < 32; ++d) s += qv[d]*kr[d];
    sc[m] = s*scale;
  }
  __syncthreads();

  float lm = -1e30f;
  for (int m = tid; m < KSEL; m += 256) lm = fmaxf(lm, sc[m]);
  #pragma unroll
  for (int off = 32; off > 0; off >>= 1) lm = fmaxf(lm, __shfl_down(lm, off));
  if ((tid & 63) == 0) red[tid >> 6] = lm;
  __syncthreads();
  if (tid == 0) s_mx = fmaxf(fmaxf(red[0], red[1]), fmaxf(red[2], red[3]));
  __syncthreads();
  const float mx = s_mx;

  float ls = 0.f;
  for (int m = tid; m < KSEL; m += 256) {
    float pv = expf(sc[m] - mx);
    sc[m] = pv;
    ls += pv;
  }
  #pragma unroll
  for (int off = 32; off > 0; off >>= 1) ls += __shfl_down(ls, off);
  if ((tid & 63) == 0) red[tid >> 6] = ls;
  __syncthreads();
  if (tid == 0) s_sum = red[0]+red[1]+red[2]+red[3];
  __syncthreads();

  const int d = tid & 31, g = tid >> 5;
  float a = 0.f;
  for (int m = g; m < KSEL; m += 8) a += sc[m]*vb[m*256 + h*32 + d];
  part[g][d] = a;
  __syncthreads();
  if (tid < 32) {
    float s = 0.f;
    #pragma unroll
    for (int gg = 0; gg < 8; ++gg) s += part[gg][tid];
    ctx[n*256 + h*32 + tid] = s / s_sum;
  }
}

// ---------------------------------------------------------------------------
__global__ void __launch_bounds__(256) copy_kernel(
    const float4* __restrict__ src, float4* __restrict__ dst)
{
  const int i = blockIdx.x*256 + threadIdx.x;
  dst[i] = src[i];
}

__global__ void __launch_bounds__(256) scatter_kernel(
    const float* __restrict__ down, const float* __restrict__ gate,
    const int* __restrict__ sel, const float* __restrict__ att,
    float* __restrict__ out)
{
  const int n = blockIdx.x, c = threadIdx.x;
  const int l = sel[n];
  const float g = gate[l];
  const float dv = down[c*LL + l];
  out[c*LL + l] = g*att[n*256 + c] + (1.f - g)*dv;
}

// ---------------------------------------------------------------------------
extern "C" void kernel_launch(void* const* d_in, const int* in_sizes, int n_in,
                              void* d_out, int out_size, void* d_ws, size_t ws_size,
                              hipStream_t stream)
{
  (void)in_sizes; (void)n_in; (void)out_size; (void)ws_size;
  const float* down   = (const float*)d_in[0];
  const float* swinT  = (const float*)d_in[1];
  const float* wt_w   = (const float*)d_in[2];
  const float* wt_b   = (const float*)d_in[3];
  const float* ct_w   = (const float*)d_in[4];
  const float* ct_b   = (const float*)d_in[5];
  const float* up_w   = (const float*)d_in[6];
  const float* up_b   = (const float*)d_in[7];
  const float* gate_w = (const float*)d_in[8];
  const float* gate_b = (const float*)d_in[9];
  const float* ipw    = (const float*)d_in[10];
  const float* ipb    = (const float*)d_in[11];
  const float* ow     = (const float*)d_in[12];
  const float* ob     = (const float*)d_in[13];
  float* out = (float*)d_out;

  char* wsp = (char*)d_ws;
  size_t off = 0;
  auto take = [&](size_t bytes) -> void* {
    void* r = wsp + off;
    off += (bytes + 255) & ~(size_t)255;
    return r;
  };
  float* bufA  = (float*)take((size_t)256*66564*sizeof(float)); // 68.2 MB
  float* bufB  = (float*)take((size_t)256*66564*sizeof(float)); // 68.2 MB
  float* gateb = (float*)take((size_t)LL*sizeof(float));
  int*   sel   = (int*)  take(4096);
  float* WT    = (float*)take((size_t)768*256*sizeof(float));
  float* OWT   = (float*)take((size_t)256*256*sizeof(float));
  float* q_in  = (float*)take((size_t)KSEL*256*sizeof(float));
  float* kv_in = (float*)take((size_t)KSEL*256*sizeof(float));
  float* qkv   = (float*)take((size_t)3*KSEL*256*sizeof(float));
  float* ctx   = (float*)take((size_t)KSEL*256*sizeof(float));
  float* att   = (float*)take((size_t)KSEL*256*sizeof(float));

  // ---- decoder pipeline ----
  zb_kernel<<<64, 256, 0, stream>>>(bufA, 10, bufB, 18);
  conv1x1_kernel<<<256, 64, 0, stream>>>(swinT, wt_w, wt_b, bufA);
  int hi = 8;
  for (int s = 0; s < 5; ++s) {
    const int ho = hi*2;
    if (s > 0)
      zb_kernel<<<64, 256, 0, stream>>>(bufA, hi+2, bufB, ho+2);
    dim3 gT((ho + 31)/32, (ho + 31)/32, 32);
    convt_kernel<<<gT, 256, 0, stream>>>(bufA, ct_w + (size_t)s*256*256*16,
                                         ct_b + s*256, bufB, hi, hi);
    dim3 g3(ho/16, ho/16, 16);
    conv3_kernel<<<g3, 256, 0, stream>>>(bufB, up_w + (size_t)s*256*256*9,
                                         up_b + s*256, bufA, ho, ho);
    hi = ho;
  }

  // ---- gate + top-k ----
  gate_kernel<<<256, 256, 0, stream>>>(down, gate_w, gate_b, gateb);
  topk_kernel<<<1, 1024, 0, stream>>>(gateb, sel);

  // ---- attention ----
  transpose_kernel<<<dim3(8, 24), 256, 0, stream>>>(ipw, WT, 768, 256);
  transpose_kernel<<<dim3(8, 8), 256, 0, stream>>>(ow, OWT, 256, 256);
  gather_kernel<<<KSEL, 256, 0, stream>>>(down, bufA, sel, q_in, kv_in);
  rowgemm_kernel<<<dim3(41, 3), 256, 0, stream>>>(WT, 768, q_in, kv_in, ipb, qkv, KSEL);
  attn_kernel<<<dim3(KSEL, 8), 256, 0, stream>>>(qkv, qkv + KSEL*256, qkv + 2*KSEL*256, ctx);
  rowgemm_kernel<<<dim3(41, 1), 256, 0, stream>>>(OWT, 256, ctx, ctx, ob, att, KSEL);

  // ---- output: copy down, then blend the selected pixels ----
  copy_kernel<<<16384, 256, 0, stream>>>((const float4*)down, (float4*)out);
  scatter_kernel<<<KSEL, 256, 0, stream>>>(down, gateb, sel, att, out);
}

// Round 2
// 1856.972 us; speedup vs baseline: 4.3243x; 4.3243x over previous
//
#include <hip/hip_runtime.h>

#define LL 65536      // H*W
#define KSEL 655      // top-k count

typedef unsigned short u16;
typedef __attribute__((ext_vector_type(8))) short s16x8;
typedef __attribute__((ext_vector_type(4))) float f32x4;

__device__ __forceinline__ u16 f2bf(float v) {
  unsigned u = __float_as_uint(v);
  u += 0x7FFFu + ((u >> 16) & 1u);
  return (u16)(u >> 16);
}
__device__ __forceinline__ float bf2f(u16 h) {
  return __uint_as_float(((unsigned)h) << 16);
}

// ---------------------------------------------------------------------------
// Zero the borders of a padded split-activation buffer:
// layout [16 planes (g=0..7 hi, 8..15 lo)][(H+2)][(W+2)][32ci], resolution H.
// ---------------------------------------------------------------------------
__global__ void zb2_kernel(u16* __restrict__ buf, int H)
{
  const int H2 = H + 2;
  const int PS = H2*H2*32;
  const int per = (4*H2 - 4)*32;
  const int tot = 16*per;
  for (int t = blockIdx.x*blockDim.x + threadIdx.x; t < tot; t += gridDim.x*blockDim.x) {
    const int pl = t / per, e = t - pl*per;
    const int pix = e >> 5, cw = e & 31;
    int y, x;
    if (pix < H2)        { y = 0;      x = pix; }
    else if (pix < 2*H2) { y = H2-1;   x = pix - H2; }
    else { int k2 = pix - 2*H2; y = 1 + (k2 >> 1); x = (k2 & 1) ? (H2-1) : 0; }
    buf[(size_t)pl*PS + ((size_t)(y*H2 + x))*32 + cw] = 0;
  }
}

// ---------------------------------------------------------------------------
// Weight prep: conv3x3.  up_w (5, co256, ci256, 3,3) fp32 ->
// W3: per stage [2 (hi/lo)][tap9][co][ci] bf16.
// ---------------------------------------------------------------------------
__global__ void prep_w3_kernel(const float* __restrict__ up_w, u16* __restrict__ W3)
{
  const size_t i = (size_t)blockIdx.x*256 + threadIdx.x;
  if (i >= (size_t)5*9*65536) return;
  const int s = (int)(i / (9*65536));
  const int rr = (int)(i - (size_t)s*(9*65536));
  const int tap = rr / 65536, e = rr - tap*65536;
  const int co = e >> 8, ci = e & 255;
  const float v = up_w[((size_t)(s*65536 + co*256 + ci))*9 + tap];
  const u16 h = f2bf(v);
  const size_t ob = (size_t)s*(2*9*65536);
  W3[ob + (size_t)tap*65536 + e] = h;
  W3[ob + (size_t)9*65536 + (size_t)tap*65536 + e] = f2bf(v - bf2f(h));
}

// ---------------------------------------------------------------------------
// Weight prep: convT.  ct_w (5, ci256, co256, 4,4) fp32 ->
// W4: per stage [2][16 (p*4+dt)][co][ci] bf16, where p=(py,px), dt=(dy,dx),
// ky = 3-py-2dy, kx = 3-px-2dx.
// ---------------------------------------------------------------------------
__global__ void prep_wt_kernel(const float* __restrict__ ct_w, u16* __restrict__ W4)
{
  const size_t i = (size_t)blockIdx.x*256 + threadIdx.x;
  if (i >= (size_t)5*16*65536) return;
  const int s = (int)(i / (16*65536));
  const int rr = (int)(i - (size_t)s*(16*65536));
  const int pdt = rr / 65536, e = rr - pdt*65536;
  const int co = e >> 8, ci = e & 255;
  const int p = pdt >> 2, dt = pdt & 3;
  const int py = p >> 1, px = p & 1, dy = dt >> 1, dx = dt & 1;
  const int ky = 3 - py - 2*dy, kx = 3 - px - 2*dx;
  const float v = ct_w[((size_t)((s*256 + ci)*256 + co))*16 + ky*4 + kx];
  const u16 h = f2bf(v);
  const size_t ob = (size_t)s*(2*16*65536);
  W4[ob + (size_t)pdt*65536 + e] = h;
  W4[ob + (size_t)16*65536 + (size_t)pdt*65536 + e] = f2bf(v - bf2f(h));
}

// ---------------------------------------------------------------------------
// 1x1 conv: swinT (768,8,8) -> split activation buffer at res 8 (padded 10).
// ---------------------------------------------------------------------------
__global__ void __launch_bounds__(64) conv1x1_kernel(
    const float* __restrict__ swinT, const float* __restrict__ w,
    const float* __restrict__ b, u16* __restrict__ out)
{
  const int co = blockIdx.x, pp = threadIdx.x;
  float acc = b[co];
  for (int ci = 0; ci < 768; ++ci)
    acc += swinT[ci*64 + pp] * w[co*768 + ci];
  const int py = pp >> 3, px = pp & 7;
  const int g = co >> 5, cw = co & 31;
  const size_t o = (size_t)g*3200 + ((size_t)((py+1)*10 + px+1))*32 + cw;
  const u16 h = f2bf(acc);
  out[o] = h;
  out[o + (size_t)8*3200] = f2bf(acc - bf2f(h));
}

// ---------------------------------------------------------------------------
// Shared staging: 18x18 pixel tile x 32 ci (hi+lo) into LDS.
// ---------------------------------------------------------------------------
__device__ __forceinline__ void stage_tile(
    const u16* __restrict__ in, u16* __restrict__ tile,
    int ch, int PS, int H2, int Y0, int X0, int tid)
{
  for (int t = tid; t < 2592; t += 256) {
    const int which = (t >= 1296) ? 1 : 0;
    const int e = which ? t - 1296 : t;
    const int p = e >> 2, c8 = e & 3;
    const int r = p / 18, c = p - r*18;
    const int gr = Y0 + r, gc = X0 + c;
    s16x8 v = {};
    if (gr < H2 && gc < H2)
      v = *(const s16x8*)&in[(size_t)(which*8 + ch)*PS + ((size_t)(gr*H2 + gc))*32 + c8*8];
    *(s16x8*)&tile[which*10368 + p*32 + c8*8] = v;
  }
}

// ---------------------------------------------------------------------------
// conv3x3 via MFMA (split bf16): in res H -> out res H (both padded layout).
// grid (H/16, H/16, 4 co-blocks of 64), block 256 (4 waves; wave w = rows 4w..4w+3)
// ---------------------------------------------------------------------------
__global__ void __launch_bounds__(256, 2) conv3_mfma(
    const u16* __restrict__ in, const u16* __restrict__ W,
    const float* __restrict__ bias, u16* __restrict__ out, int H)
{
  const int H2 = H + 2;
  const int PS = H2*H2*32;
  const int tid = threadIdx.x;
  const int lane = tid & 63, wv = tid >> 6;
  const int lx = lane & 15, kg = lane >> 4;
  const int X0 = blockIdx.x*16, Y0 = blockIdx.y*16;
  const int cob = blockIdx.z;
  const int yl0 = wv*4;

  __shared__ u16 tile[2*10368];
  f32x4 acc[4][4] = {};

  for (int ch = 0; ch < 8; ++ch) {
    stage_tile(in, tile, ch, PS, H2, Y0, X0, tid);
    __syncthreads();
    for (int tap = 0; tap < 9; ++tap) {
      const int dy = tap/3, dx = tap - dy*3;
      s16x8 bh[4], bl[4];
      #pragma unroll
      for (int n = 0; n < 4; ++n) {
        const int co = cob*64 + n*16 + lx;
        const size_t wo = ((size_t)(tap*256 + co))*256 + ch*32 + kg*8;
        bh[n] = *(const s16x8*)&W[wo];
        bl[n] = *(const s16x8*)&W[wo + (size_t)9*65536];
      }
      s16x8 ah[4], al[4];
      #pragma unroll
      for (int mi = 0; mi < 4; ++mi) {
        const int ad = ((yl0 + mi + dy)*18 + lx + dx)*32 + kg*8;
        ah[mi] = *(const s16x8*)&tile[ad];
        al[mi] = *(const s16x8*)&tile[10368 + ad];
      }
      #pragma unroll
      for (int mi = 0; mi < 4; ++mi)
        #pragma unroll
        for (int n = 0; n < 4; ++n) {
          acc[mi][n] = __builtin_amdgcn_mfma_f32_16x16x32_bf16(ah[mi], bh[n], acc[mi][n], 0, 0, 0);
          acc[mi][n] = __builtin_amdgcn_mfma_f32_16x16x32_bf16(ah[mi], bl[n], acc[mi][n], 0, 0, 0);
          acc[mi][n] = __builtin_amdgcn_mfma_f32_16x16x32_bf16(al[mi], bh[n], acc[mi][n], 0, 0, 0);
        }
    }
    __syncthreads();
  }

  #pragma unroll
  for (int mi = 0; mi < 4; ++mi) {
    const int y = Y0 + yl0 + mi;
    if (y >= H) continue;
    #pragma unroll
    for (int n = 0; n < 4; ++n) {
      const int co = cob*64 + n*16 + lx;
      const float bv = bias[co];
      const int g = co >> 5, cw = co & 31;
      #pragma unroll
      for (int j = 0; j < 4; ++j) {
        const int x = X0 + kg*4 + j;
        if (x >= H) continue;
        const float v = acc[mi][n][j] + bv;
        const u16 h = f2bf(v);
        const size_t o = (size_t)g*PS + ((size_t)((y+1)*H2 + x+1))*32 + cw;
        out[o] = h;
        out[o + (size_t)8*PS] = f2bf(v - bf2f(h));
      }
    }
  }
}

// ---------------------------------------------------------------------------
// ConvTranspose2d k4 s2 p1 + ReLU via MFMA (split bf16), one parity per z-slice.
// grid (ceil(Hin/16), ceil(Hin/16), 16: z = parity*4 + co-block), block 256.
// ---------------------------------------------------------------------------
__global__ void __launch_bounds__(256, 2) convt_mfma(
    const u16* __restrict__ in, const u16* __restrict__ W,
    const float* __restrict__ bias, u16* __restrict__ out, int Hin)
{
  const int Hout = Hin*2;
  const int H2i = Hin + 2, H2o = Hout + 2;
  const int PSi = H2i*H2i*32, PSo = H2o*H2o*32;
  const int tid = threadIdx.x;
  const int lane = tid & 63, wv = tid >> 6;
  const int lx = lane & 15, kg = lane >> 4;
  const int X0 = blockIdx.x*16, Y0 = blockIdx.y*16;
  const int p = blockIdx.z >> 2, cob = blockIdx.z & 3;
  const int py = p >> 1, px = p & 1;
  const int yl0 = wv*4;

  __shared__ u16 tile[2*10368];
  f32x4 acc[4][4] = {};

  for (int ch = 0; ch < 8; ++ch) {
    stage_tile(in, tile, ch, PSi, H2i, Y0, X0, tid);
    __syncthreads();
    for (int dt = 0; dt < 4; ++dt) {
      const int dy = dt >> 1, dx = dt & 1;
      s16x8 bh[4], bl[4];
      #pragma unroll
      for (int n = 0; n < 4; ++n) {
        const int co = cob*64 + n*16 + lx;
        const size_t wo = ((size_t)((p*4 + dt)*256 + co))*256 + ch*32 + kg*8;
        bh[n] = *(const s16x8*)&W[wo];
        bl[n] = *(const s16x8*)&W[wo + (size_t)16*65536];
      }
      s16x8 ah[4], al[4];
      #pragma unroll
      for (int mi = 0; mi < 4; ++mi) {
        const int ad = ((yl0 + mi + py + dy)*18 + lx + px + dx)*32 + kg*8;
        ah[mi] = *(const s16x8*)&tile[ad];
        al[mi] = *(const s16x8*)&tile[10368 + ad];
      }
      #pragma unroll
      for (int mi = 0; mi < 4; ++mi)
        #pragma unroll
        for (int n = 0; n < 4; ++n) {
          acc[mi][n] = __builtin_amdgcn_mfma_f32_16x16x32_bf16(ah[mi], bh[n], acc[mi][n], 0, 0, 0);
          acc[mi][n] = __builtin_amdgcn_mfma_f32_16x16x32_bf16(ah[mi], bl[n], acc[mi][n], 0, 0, 0);
          acc[mi][n] = __builtin_amdgcn_mfma_f32_16x16x32_bf16(al[mi], bh[n], acc[mi][n], 0, 0, 0);
        }
    }
    __syncthreads();
  }

  #pragma unroll
  for (int mi = 0; mi < 4; ++mi) {
    const int yi = Y0 + yl0 + mi;
    if (yi >= Hin) continue;
    const int Y = 2*yi + py;
    #pragma unroll
    for (int n = 0; n < 4; ++n) {
      const int co = cob*64 + n*16 + lx;
      const float bv = bias[co];
      const int g = co >> 5, cw = co & 31;
      #pragma unroll
      for (int j = 0; j < 4; ++j) {
        const int xi = X0 + kg*4 + j;
        if (xi >= Hin) continue;
        const int X = 2*xi + px;
        const float v = fmaxf(acc[mi][n][j] + bv, 0.f);
        const u16 h = f2bf(v);
        const size_t o = (size_t)g*PSo + ((size_t)((Y+1)*H2o + X+1))*32 + cw;
        out[o] = h;
        out[o + (size_t)8*PSo] = f2bf(v - bf2f(h));
      }
    }
  }
}

// ---------------------------------------------------------------------------
// gate[l] = sigmoid(sum_c down[c*L+l]*gw[c] + gb)
// ---------------------------------------------------------------------------
__global__ void __launch_bounds__(256) gate_kernel(
    const float* __restrict__ down, const float* __restrict__ gw,
    const float* __restrict__ gb, float* __restrict__ gate)
{
  const int l = blockIdx.x*256 + threadIdx.x;
  float a0 = 0.f, a1 = 0.f, a2 = 0.f, a3 = 0.f;
  for (int c = 0; c < 256; c += 4) {
    a0 += down[(c+0)*LL + l] * gw[c+0];
    a1 += down[(c+1)*LL + l] * gw[c+1];
    a2 += down[(c+2)*LL + l] * gw[c+2];
    a3 += down[(c+3)*LL + l] * gw[c+3];
  }
  const float a = (a0+a1) + (a2+a3) + gb[0];
  gate[l] = 1.f / (1.f + expf(-a));
}

// ---------------------------------------------------------------------------
// Exact top-K selection (set semantics, ties -> lowest index), single block.
// ---------------------------------------------------------------------------
__global__ void __launch_bounds__(1024) topk_kernel(
    const float* __restrict__ gate, int* __restrict__ sel)
{
  __shared__ unsigned hist[256];
  __shared__ unsigned s_pref;
  __shared__ int s_kk;
  __shared__ int wsum[16];
  __shared__ int s_base;
  const int tid = threadIdx.x;

  unsigned pref = 0; int kk = KSEL;
  for (int pass = 0; pass < 4; ++pass) {
    const int shift = 24 - 8*pass;
    if (tid < 256) hist[tid] = 0;
    __syncthreads();
    for (int i = tid; i < LL; i += 1024) {
      unsigned u = __float_as_uint(gate[i]);
      bool ok;
      if (pass == 0) ok = true;
      else           ok = ((u >> (shift + 8)) == pref);
      if (ok) atomicAdd(&hist[(u >> shift) & 255u], 1u);
    }
    __syncthreads();
    if (tid == 0) {
      int cum = 0, b = 255;
      for (; b >= 0; --b) {
        int c = (int)hist[b];
        if (cum + c >= kk) break;
        cum += c;
      }
      if (b < 0) b = 0;
      s_pref = (pref << 8) | (unsigned)b;
      s_kk = kk - cum;
    }
    __syncthreads();
    pref = s_pref; kk = s_kk;
    __syncthreads();
  }
  const unsigned T = pref;
  const int need = kk;
  const int lane = tid & 63, wv = tid >> 6;

  if (tid == 0) s_base = 0;
  __syncthreads();
  for (int i0 = 0; i0 < LL; i0 += 1024) {
    const unsigned u = __float_as_uint(gate[i0 + tid]);
    const bool f = (u > T);
    const unsigned long long m = __ballot(f);
    const int pre = __popcll(m & ((1ull << lane) - 1ull));
    if (lane == 0) wsum[wv] = __popcll(m);
    __syncthreads();
    if (tid == 0) {
      int s = s_base;
      for (int w = 0; w < 16; ++w) { int t = wsum[w]; wsum[w] = s; s += t; }
      s_base = s;
    }
    __syncthreads();
    if (f) sel[wsum[wv] + pre] = i0 + tid;
    __syncthreads();
  }
  const int cgt = s_base;
  __syncthreads();
  if (tid == 0) s_base = 0;
  __syncthreads();
  for (int i0 = 0; i0 < LL; i0 += 1024) {
    const unsigned u = __float_as_uint(gate[i0 + tid]);
    const bool f = (u == T);
    const unsigned long long m = __ballot(f);
    const int pre = __popcll(m & ((1ull << lane) - 1ull));
    if (lane == 0) wsum[wv] = __popcll(m);
    __syncthreads();
    if (tid == 0) {
      int s = s_base;
      for (int w = 0; w < 16; ++w) { int t = wsum[w]; wsum[w] = s; s += t; }
      s_base = s;
    }
    __syncthreads();
    const int pos = wsum[wv] + pre;
    if (f && pos < need) sel[cgt + pos] = i0 + tid;
    __syncthreads();
  }
}

// ---------------------------------------------------------------------------
__global__ void __launch_bounds__(256) transpose_kernel(
    const float* __restrict__ in, float* __restrict__ out, int R, int Ck)
{
  __shared__ float t[32][33];
  const int bx = blockIdx.x*32, by = blockIdx.y*32;
  const int x = threadIdx.x & 31, y4 = threadIdx.x >> 5;
  #pragma unroll
  for (int i = 0; i < 4; ++i) {
    int r = by + y4 + i*8, c = bx + x;
    t[y4 + i*8][x] = (r < R && c < Ck) ? in[r*Ck + c] : 0.f;
  }
  __syncthreads();
  #pragma unroll
  for (int i = 0; i < 4; ++i) {
    int c = bx + y4 + i*8, r = by + x;
    if (c < Ck && r < R) out[c*R + r] = t[x][y4 + i*8];
  }
}

// ---------------------------------------------------------------------------
// Gather: q from down (C,L); kv from final split buffer (res 256, padded 258).
// ---------------------------------------------------------------------------
__global__ void __launch_bounds__(256) gather_kernel(
    const float* __restrict__ down, const u16* __restrict__ xf,
    const int* __restrict__ sel, float* __restrict__ q_in, float* __restrict__ kv_in)
{
  const int n = blockIdx.x, c = threadIdx.x;
  const int l = sel[n];
  q_in[n*256 + c] = down[c*LL + l];
  const int pr = (l >> 8) + 1, pc = (l & 255) + 1;
  const size_t PS = (size_t)258*258*32;
  const size_t o = (size_t)(c >> 5)*PS + ((size_t)(pr*258 + pc))*32 + (c & 31);
  kv_in[n*256 + c] = bf2f(xf[o]) + bf2f(xf[o + (size_t)8*PS]);
}

// ---------------------------------------------------------------------------
__global__ void __launch_bounds__(256) rowgemm_kernel(
    const float* __restrict__ WT, int wld,
    const float* __restrict__ srcA, const float* __restrict__ srcB,
    const float* __restrict__ bias, float* __restrict__ out, int N)
{
  const int g = blockIdx.y;
  const int tid = threadIdx.x;
  const int co = g*256 + tid;
  const float* src = (g == 0) ? srcA : srcB;
  float* outg = out + (size_t)g*(KSEL*256);
  __shared__ float Bl[16][256];
  const int n0 = blockIdx.x*16;
  #pragma unroll
  for (int j = 0; j < 16; ++j) {
    int n = n0 + j;
    Bl[j][tid] = (n < N) ? src[n*256 + tid] : 0.f;
  }
  __syncthreads();
  float acc[16];
  const float bv = bias[co];
  #pragma unroll
  for (int j = 0; j < 16; ++j) acc[j] = bv;
  #pragma unroll 4
  for (int ci = 0; ci < 256; ++ci) {
    const float w = WT[ci*wld + co];
    #pragma unroll
    for (int j = 0; j < 16; ++j) acc[j] += Bl[j][ci]*w;
  }
  #pragma unroll
  for (int j = 0; j < 16; ++j) {
    int n = n0 + j;
    if (n < N) outg[n*256 + tid] = acc[j];
  }
}

// ---------------------------------------------------------------------------
__global__ void __launch_bounds__(256) attn_kernel(
    const float* __restrict__ qb, const float* __restrict__ kb,
    const float* __restrict__ vb, float* __restrict__ ctx)
{
  const int n = blockIdx.x, h = blockIdx.y;
  const int tid = threadIdx.x;
  __shared__ float sc[KSEL];
  __shared__ float qv[32];
  __shared__ float red[4];
  __shared__ float part[8][32];
  __shared__ float s_mx, s_sum;

  if (tid < 32) qv[tid] = qb[n*256 + h*32 + tid];
  __syncthreads();

  const float scale = 0.17677669529663687f;
  for (int m = tid; m < KSEL; m += 256) {
    const float* kr = kb + m*256 + h*32;
    float s = 0.f;
    #pragma unroll
    for (int d = 0; d < 32; ++d) s += qv[d]*kr[d];
    sc[m] = s*scale;
  }
  __syncthreads();

  float lm = -1e30f;
  for (int m = tid; m < KSEL; m += 256) lm = fmaxf(lm, sc[m]);
  #pragma unroll
  for (int off = 32; off > 0; off >>= 1) lm = fmaxf(lm, __shfl_down(lm, off));
  if ((tid & 63) == 0) red[tid >> 6] = lm;
  __syncthreads();
  if (tid == 0) s_mx = fmaxf(fmaxf(red[0], red[1]), fmaxf(red[2], red[3]));
  __syncthreads();
  const float mx = s_mx;

  float ls = 0.f;
  for (int m = tid; m < KSEL; m += 256) {
    float pv = expf(sc[m] - mx);
    sc[m] = pv;
    ls += pv;
  }
  #pragma unroll
  for (int off = 32; off > 0; off >>= 1) ls += __shfl_down(ls, off);
  if ((tid & 63) == 0) red[tid >> 6] = ls;
  __syncthreads();
  if (tid == 0) s_sum = red[0]+red[1]+red[2]+red[3];
  __syncthreads();

  const int d = tid & 31, g = tid >> 5;
  float a = 0.f;
  for (int m = g; m < KSEL; m += 8) a += sc[m]*vb[m*256 + h*32 + d];
  part[g][d] = a;
  __syncthreads();
  if (tid < 32) {
    float s = 0.f;
    #pragma unroll
    for (int gg = 0; gg < 8; ++gg) s += part[gg][tid];
    ctx[n*256 + h*32 + tid] = s / s_sum;
  }
}

// ---------------------------------------------------------------------------
__global__ void __launch_bounds__(256) copy_kernel(
    const float4* __restrict__ src, float4* __restrict__ dst)
{
  const int i = blockIdx.x*256 + threadIdx.x;
  dst[i] = src[i];
}

__global__ void __launch_bounds__(256) scatter_kernel(
    const float* __restrict__ down, const float* __restrict__ gate,
    const int* __restrict__ sel, const float* __restrict__ att,
    float* __restrict__ out)
{
  const int n = blockIdx.x, c = threadIdx.x;
  const int l = sel[n];
  const float g = gate[l];
  const float dv = down[c*LL + l];
  out[c*LL + l] = g*att[n*256 + c] + (1.f - g)*dv;
}

// ---------------------------------------------------------------------------
extern "C" void kernel_launch(void* const* d_in, const int* in_sizes, int n_in,
                              void* d_out, int out_size, void* d_ws, size_t ws_size,
                              hipStream_t stream)
{
  (void)in_sizes; (void)n_in; (void)out_size; (void)ws_size;
  const float* down   = (const float*)d_in[0];
  const float* swinT  = (const float*)d_in[1];
  const float* wt_w   = (const float*)d_in[2];
  const float* wt_b   = (const float*)d_in[3];
  const float* ct_w   = (const float*)d_in[4];
  const float* ct_b   = (const float*)d_in[5];
  const float* up_w   = (const float*)d_in[6];
  const float* up_b   = (const float*)d_in[7];
  const float* gate_w = (const float*)d_in[8];
  const float* gate_b = (const float*)d_in[9];
  const float* ipw    = (const float*)d_in[10];
  const float* ipb    = (const float*)d_in[11];
  const float* ow     = (const float*)d_in[12];
  const float* ob     = (const float*)d_in[13];
  float* out = (float*)d_out;

  char* wsp = (char*)d_ws;
  size_t off = 0;
  auto take = [&](size_t bytes) -> void* {
    void* r = wsp + off;
    off += (bytes + 255) & ~(size_t)255;
    return r;
  };
  u16*   A     = (u16*)  take((size_t)16*258*258*32*sizeof(u16)); // 68.2 MB
  u16*   B     = (u16*)  take((size_t)16*258*258*32*sizeof(u16)); // 68.2 MB
  u16*   W3    = (u16*)  take((size_t)5*2*9*65536*sizeof(u16));   // 11.8 MB
  u16*   W4    = (u16*)  take((size_t)5*2*16*65536*sizeof(u16));  // 21.0 MB
  float* gateb = (float*)take((size_t)LL*sizeof(float));
  int*   sel   = (int*)  take(4096);
  float* WT    = (float*)take((size_t)768*256*sizeof(float));
  float* OWT   = (float*)take((size_t)256*256*sizeof(float));
  float* q_in  = (float*)take((size_t)KSEL*256*sizeof(float));
  float* kv_in = (float*)take((size_t)KSEL*256*sizeof(float));
  float* qkv   = (float*)take((size_t)3*KSEL*256*sizeof(float));
  float* ctx   = (float*)take((size_t)KSEL*256*sizeof(float));
  float* att   = (float*)take((size_t)KSEL*256*sizeof(float));

  // ---- weight prep ----
  prep_w3_kernel<<<(5*9*65536 + 255)/256, 256, 0, stream>>>(up_w, W3);
  prep_wt_kernel<<<(5*16*65536 + 255)/256, 256, 0, stream>>>(ct_w, W4);

  // ---- decoder pipeline ----
  auto zbBlocks = [](int H) { return (16*(4*(H+2) - 4)*32 + 255)/256; };
  zb2_kernel<<<zbBlocks(8), 256, 0, stream>>>(A, 8);
  conv1x1_kernel<<<256, 64, 0, stream>>>(swinT, wt_w, wt_b, A);
  int r = 8;
  for (int s = 0; s < 5; ++s) {
    const int o = 2*r;
    const int tI = (r + 15)/16, tO = o/16;
    zb2_kernel<<<zbBlocks(o), 256, 0, stream>>>(B, o);
    convt_mfma<<<dim3(tI, tI, 16), 256, 0, stream>>>(
        A, W4 + (size_t)s*2*16*65536, ct_b + s*256, B, r);
    zb2_kernel<<<zbBlocks(o), 256, 0, stream>>>(A, o);
    conv3_mfma<<<dim3(tO, tO, 4), 256, 0, stream>>>(
        B, W3 + (size_t)s*2*9*65536, up_b + s*256, A, o);
    r = o;
  }

  // ---- gate + top-k ----
  gate_kernel<<<256, 256, 0, stream>>>(down, gate_w, gate_b, gateb);
  topk_kernel<<<1, 1024, 0, stream>>>(gateb, sel);

  // ---- attention ----
  transpose_kernel<<<dim3(8, 24), 256, 0, stream>>>(ipw, WT, 768, 256);
  transpose_kernel<<<dim3(8, 8), 256, 0, stream>>>(ow, OWT, 256, 256);
  gather_kernel<<<KSEL, 256, 0, stream>>>(down, A, sel, q_in, kv_in);
  rowgemm_kernel<<<dim3(41, 3), 256, 0, stream>>>(WT, 768, q_in, kv_in, ipb, qkv, KSEL);
  attn_kernel<<<dim3(KSEL, 8), 256, 0, stream>>>(qkv, qkv + KSEL*256, qkv + 2*KSEL*256, ctx);
  rowgemm_kernel<<<dim3(41, 1), 256, 0, stream>>>(OWT, 256, ctx, ctx, ob, att, KSEL);

  // ---- output: copy down, then blend the selected pixels ----
  copy_kernel<<<16384, 256, 0, stream>>>((const float4*)down, (float4*)out);
  scatter_kernel<<<KSEL, 256, 0, stream>>>(down, gateb, sel, att, out);
}

// Round 3
// 1478.447 us; speedup vs baseline: 5.4315x; 1.2560x over previous
//
#include <hip/hip_runtime.h>

#define LL 65536      // H*W
#define KSEL 655      // top-k count
#define TPAD 36       // LDS per-pixel stride in u16 (32 data + 4 pad)
#define TILE_HALF (18*18*TPAD)
#define EQCAP 8192

typedef unsigned short u16;
typedef __attribute__((ext_vector_type(8))) short s16x8;
typedef __attribute__((ext_vector_type(4))) float f32x4;

__device__ __forceinline__ u16 f2bf(float v) {
  unsigned u = __float_as_uint(v);
  u += 0x7FFFu + ((u >> 16) & 1u);
  return (u16)(u >> 16);
}
__device__ __forceinline__ float bf2f(u16 h) {
  return __uint_as_float(((unsigned)h) << 16);
}

// ---------------------------------------------------------------------------
// Zero the borders of a padded split-activation buffer:
// layout [16 planes (g=0..7 hi, 8..15 lo)][(H+2)][(W+2)][32ci].
// ---------------------------------------------------------------------------
__global__ void zb2_kernel(u16* __restrict__ buf, int H)
{
  const int H2 = H + 2;
  const int PS = H2*H2*32;
  const int per = (4*H2 - 4)*32;
  const int tot = 16*per;
  for (int t = blockIdx.x*blockDim.x + threadIdx.x; t < tot; t += gridDim.x*blockDim.x) {
    const int pl = t / per, e = t - pl*per;
    const int pix = e >> 5, cw = e & 31;
    int y, x;
    if (pix < H2)        { y = 0;      x = pix; }
    else if (pix < 2*H2) { y = H2-1;   x = pix - H2; }
    else { int k2 = pix - 2*H2; y = 1 + (k2 >> 1); x = (k2 & 1) ? (H2-1) : 0; }
    buf[(size_t)pl*PS + ((size_t)(y*H2 + x))*32 + cw] = 0;
  }
}

// ---------------------------------------------------------------------------
// Weight prep conv3x3: up_w (5, co256, ci256, 3,3) fp32 ->
// W3 flat layout: (((((s*2+hl)*9+tap)*4+cob)*4+n)*8+ch)*512 + lane*8 + e
// where co = cob*64+n*16+(lane&15), ci = ch*32+(lane>>4)*8+e.
// ---------------------------------------------------------------------------
__global__ void prep_w3_kernel(const float* __restrict__ up_w, u16* __restrict__ W3)
{
  const size_t i = (size_t)blockIdx.x*256 + threadIdx.x;
  if (i >= (size_t)5898240) return;
  unsigned t = (unsigned)i;
  const int e = t & 7; t >>= 3;
  const int lane = t & 63; t >>= 6;
  const int ch = t & 7; t >>= 3;
  const int n = t & 3; t >>= 2;
  const int cob = t & 3; t >>= 2;
  const int tap = t % 9; t /= 9;
  const int hl = t & 1; const int s = t >> 1;
  const int co = cob*64 + n*16 + (lane & 15);
  const int ci = ch*32 + (lane >> 4)*8 + e;
  const float v = up_w[((size_t)(s*65536 + co*256 + ci))*9 + tap];
  const u16 h = f2bf(v);
  W3[i] = hl ? f2bf(v - bf2f(h)) : h;
}

// ---------------------------------------------------------------------------
// Weight prep convT: ct_w (5, ci256, co256, 4,4) fp32 ->
// W4 flat: (((((s*2+hl)*16+pdt)*4+cob)*4+n)*8+ch)*512 + lane*8 + e
// pdt = p*4+dt, p=(py,px), dt=(dy,dx); ky=3-py-2dy, kx=3-px-2dx.
// ---------------------------------------------------------------------------
__global__ void prep_wt_kernel(const float* __restrict__ ct_w, u16* __restrict__ W4)
{
  const size_t i = (size_t)blockIdx.x*256 + threadIdx.x;
  if (i >= (size_t)10485760) return;
  unsigned t = (unsigned)i;
  const int e = t & 7; t >>= 3;
  const int lane = t & 63; t >>= 6;
  const int ch = t & 7; t >>= 3;
  const int n = t & 3; t >>= 2;
  const int cob = t & 3; t >>= 2;
  const int pdt = t & 15; t >>= 4;
  const int hl = t & 1; const int s = t >> 1;
  const int co = cob*64 + n*16 + (lane & 15);
  const int ci = ch*32 + (lane >> 4)*8 + e;
  const int p = pdt >> 2, dt = pdt & 3;
  const int py = p >> 1, px = p & 1, dy = dt >> 1, dx = dt & 1;
  const int ky = 3 - py - 2*dy, kx = 3 - px - 2*dx;
  const float v = ct_w[((size_t)((s*256 + ci)*256 + co))*16 + ky*4 + kx];
  const u16 h = f2bf(v);
  W4[i] = hl ? f2bf(v - bf2f(h)) : h;
}

// ---------------------------------------------------------------------------
// 1x1 conv: swinT (768,8,8) -> split activation buffer at res 8 (padded 10).
// ---------------------------------------------------------------------------
__global__ void __launch_bounds__(64) conv1x1_kernel(
    const float* __restrict__ swinT, const float* __restrict__ w,
    const float* __restrict__ b, u16* __restrict__ out)
{
  const int co = blockIdx.x, pp = threadIdx.x;
  float acc = b[co];
  for (int ci = 0; ci < 768; ++ci)
    acc += swinT[ci*64 + pp] * w[co*768 + ci];
  const int py = pp >> 3, px = pp & 7;
  const int g = co >> 5, cw = co & 31;
  const size_t o = (size_t)g*3200 + ((size_t)((py+1)*10 + px+1))*32 + cw;
  const u16 h = f2bf(acc);
  out[o] = h;
  out[o + (size_t)8*3200] = f2bf(acc - bf2f(h));
}

// ---------------------------------------------------------------------------
// Stage 18x18 pixel tile x 32 ci (hi+lo) into LDS (padded pixel stride).
// ---------------------------------------------------------------------------
__device__ __forceinline__ void stage_tile(
    const u16* __restrict__ in, u16* __restrict__ tile,
    int ch, int PS, int H2, int Y0, int X0, int tid)
{
  for (int t = tid; t < 2592; t += 256) {
    const int which = (t >= 1296) ? 1 : 0;
    const int e = which ? t - 1296 : t;
    const int p = e >> 2, c8 = e & 3;
    const int r = p / 18, c = p - r*18;
    const int gr = Y0 + r, gc = X0 + c;
    s16x8 v = {};
    if (gr < H2 && gc < H2)
      v = *(const s16x8*)&in[(size_t)(which*8 + ch)*PS + ((size_t)(gr*H2 + gc))*32 + c8*8];
    *(s16x8*)&tile[which*TILE_HALF + p*TPAD + c8*8] = v;
  }
}

// ---------------------------------------------------------------------------
// conv3x3 via MFMA (split bf16), dx-outer tap grouping, coalesced weights.
// grid (H/16, H/16, 4 co-blocks of 64), block 256.
// ---------------------------------------------------------------------------
__global__ void __launch_bounds__(256, 2) conv3_mfma(
    const u16* __restrict__ in, const u16* __restrict__ W,
    const float* __restrict__ bias, u16* __restrict__ out, int H)
{
  const int H2 = H + 2;
  const int PS = H2*H2*32;
  const int tid = threadIdx.x;
  const int lane = tid & 63, wv = tid >> 6;
  const int lx = lane & 15, kg = lane >> 4;
  const int X0 = blockIdx.x*16, Y0 = blockIdx.y*16;
  const int cob = blockIdx.z;
  const int yl0 = wv*4;

  __shared__ u16 tile[2*TILE_HALF];
  f32x4 acc[4][4] = {};
  const u16* Wl = W + lane*8;

  for (int ch = 0; ch < 8; ++ch) {
    stage_tile(in, tile, ch, PS, H2, Y0, X0, tid);
    __syncthreads();
    #pragma unroll
    for (int dxg = 0; dxg < 3; ++dxg) {
      s16x8 ah[6], al[6];
      #pragma unroll
      for (int r = 0; r < 6; ++r) {
        const int ad = ((yl0 + r)*18 + lx + dxg)*TPAD + kg*8;
        ah[r] = *(const s16x8*)&tile[ad];
        al[r] = *(const s16x8*)&tile[TILE_HALF + ad];
      }
      #pragma unroll
      for (int dy = 0; dy < 3; ++dy) {
        const int tap = dy*3 + dxg;
        s16x8 bh[4], bl[4];
        #pragma unroll
        for (int n = 0; n < 4; ++n) {
          const int oh = (((tap*4 + cob)*4 + n)*8 + ch)*512;
          bh[n] = *(const s16x8*)&Wl[oh];
          bl[n] = *(const s16x8*)&Wl[oh + 589824];   // hl stride = 9*65536
        }
        #pragma unroll
        for (int mi = 0; mi < 4; ++mi)
          #pragma unroll
          for (int n = 0; n < 4; ++n) {
            acc[mi][n] = __builtin_amdgcn_mfma_f32_16x16x32_bf16(ah[mi+dy], bh[n], acc[mi][n], 0, 0, 0);
            acc[mi][n] = __builtin_amdgcn_mfma_f32_16x16x32_bf16(ah[mi+dy], bl[n], acc[mi][n], 0, 0, 0);
            acc[mi][n] = __builtin_amdgcn_mfma_f32_16x16x32_bf16(al[mi+dy], bh[n], acc[mi][n], 0, 0, 0);
          }
      }
    }
    __syncthreads();
  }

  #pragma unroll
  for (int mi = 0; mi < 4; ++mi) {
    const int y = Y0 + yl0 + mi;
    if (y >= H) continue;
    #pragma unroll
    for (int n = 0; n < 4; ++n) {
      const int co = cob*64 + n*16 + lx;
      const float bv = bias[co];
      const int g = co >> 5, cw = co & 31;
      #pragma unroll
      for (int j = 0; j < 4; ++j) {
        const int x = X0 + kg*4 + j;
        if (x >= H) continue;
        const float v = acc[mi][n][j] + bv;
        const u16 h = f2bf(v);
        const size_t o = (size_t)g*PS + ((size_t)((y+1)*H2 + x+1))*32 + cw;
        out[o] = h;
        out[o + (size_t)8*PS] = f2bf(v - bf2f(h));
      }
    }
  }
}

// ---------------------------------------------------------------------------
// ConvTranspose2d k4 s2 p1 + ReLU via MFMA (split bf16), parity-decomposed.
// grid (ceil(Hin/16), ceil(Hin/16), 16: z = parity*4 + co-block), block 256.
// ---------------------------------------------------------------------------
__global__ void __launch_bounds__(256, 2) convt_mfma(
    const u16* __restrict__ in, const u16* __restrict__ W,
    const float* __restrict__ bias, u16* __restrict__ out, int Hin)
{
  const int Hout = Hin*2;
  const int H2i = Hin + 2, H2o = Hout + 2;
  const int PSi = H2i*H2i*32, PSo = H2o*H2o*32;
  const int tid = threadIdx.x;
  const int lane = tid & 63, wv = tid >> 6;
  const int lx = lane & 15, kg = lane >> 4;
  const int X0 = blockIdx.x*16, Y0 = blockIdx.y*16;
  const int p = blockIdx.z >> 2, cob = blockIdx.z & 3;
  const int py = p >> 1, px = p & 1;
  const int yl0 = wv*4;

  __shared__ u16 tile[2*TILE_HALF];
  f32x4 acc[4][4] = {};
  const u16* Wl = W + lane*8;

  for (int ch = 0; ch < 8; ++ch) {
    stage_tile(in, tile, ch, PSi, H2i, Y0, X0, tid);
    __syncthreads();
    #pragma unroll
    for (int dxg = 0; dxg < 2; ++dxg) {
      s16x8 ah[5], al[5];
      #pragma unroll
      for (int r = 0; r < 5; ++r) {
        const int ad = ((yl0 + r + py)*18 + lx + px + dxg)*TPAD + kg*8;
        ah[r] = *(const s16x8*)&tile[ad];
        al[r] = *(const s16x8*)&tile[TILE_HALF + ad];
      }
      #pragma unroll
      for (int dy = 0; dy < 2; ++dy) {
        const int pdt = p*4 + dy*2 + dxg;
        s16x8 bh[4], bl[4];
        #pragma unroll
        for (int n = 0; n < 4; ++n) {
          const int oh = (((pdt*4 + cob)*4 + n)*8 + ch)*512;
          bh[n] = *(const s16x8*)&Wl[oh];
          bl[n] = *(const s16x8*)&Wl[oh + 1048576];  // hl stride = 16*65536
        }
        #pragma unroll
        for (int mi = 0; mi < 4; ++mi)
          #pragma unroll
          for (int n = 0; n < 4; ++n) {
            acc[mi][n] = __builtin_amdgcn_mfma_f32_16x16x32_bf16(ah[mi+dy], bh[n], acc[mi][n], 0, 0, 0);
            acc[mi][n] = __builtin_amdgcn_mfma_f32_16x16x32_bf16(ah[mi+dy], bl[n], acc[mi][n], 0, 0, 0);
            acc[mi][n] = __builtin_amdgcn_mfma_f32_16x16x32_bf16(al[mi+dy], bh[n], acc[mi][n], 0, 0, 0);
          }
      }
    }
    __syncthreads();
  }

  #pragma unroll
  for (int mi = 0; mi < 4; ++mi) {
    const int yi = Y0 + yl0 + mi;
    if (yi >= Hin) continue;
    const int Y = 2*yi + py;
    #pragma unroll
    for (int n = 0; n < 4; ++n) {
      const int co = cob*64 + n*16 + lx;
      const float bv = bias[co];
      const int g = co >> 5, cw = co & 31;
      #pragma unroll
      for (int j = 0; j < 4; ++j) {
        const int xi = X0 + kg*4 + j;
        if (xi >= Hin) continue;
        const int X = 2*xi + px;
        const float v = fmaxf(acc[mi][n][j] + bv, 0.f);
        const u16 h = f2bf(v);
        const size_t o = (size_t)g*PSo + ((size_t)((Y+1)*H2o + X+1))*32 + cw;
        out[o] = h;
        out[o + (size_t)8*PSo] = f2bf(v - bf2f(h));
      }
    }
  }
}

// ---------------------------------------------------------------------------
// gate[l] = sigmoid(sum_c down[c*L+l]*gw[c] + gb)
// ---------------------------------------------------------------------------
__global__ void __launch_bounds__(256) gate_kernel(
    const float* __restrict__ down, const float* __restrict__ gw,
    const float* __restrict__ gb, float* __restrict__ gate)
{
  const int l = blockIdx.x*256 + threadIdx.x;
  float a0 = 0.f, a1 = 0.f, a2 = 0.f, a3 = 0.f;
  for (int c = 0; c < 256; c += 4) {
    a0 += down[(c+0)*LL + l] * gw[c+0];
    a1 += down[(c+1)*LL + l] * gw[c+1];
    a2 += down[(c+2)*LL + l] * gw[c+2];
    a3 += down[(c+3)*LL + l] * gw[c+3];
  }
  const float a = (a0+a1) + (a2+a3) + gb[0];
  gate[l] = 1.f / (1.f + expf(-a));
}

// ---------------------------------------------------------------------------
// Grid-wide exact top-K radix select (set semantics; ties -> lowest index).
// ---------------------------------------------------------------------------
__global__ void tk_zero(unsigned* __restrict__ hist, int* __restrict__ st, int* __restrict__ cnt)
{
  const int t = threadIdx.x;
  if (t < 1024) hist[t] = 0;
  if (t == 0) { st[0] = 0; st[1] = KSEL; cnt[0] = 0; cnt[1] = 0; }
}

__global__ void __launch_bounds__(256) tk_hist(
    const float* __restrict__ gate, const int* __restrict__ st,
    unsigned* __restrict__ hist, int pass)
{
  __shared__ unsigned lh[256];
  lh[threadIdx.x] = 0;
  __syncthreads();
  const unsigned pref = (unsigned)st[0];
  const int shift = 24 - 8*pass;
  for (int i = blockIdx.x*256 + threadIdx.x; i < LL; i += gridDim.x*256) {
    const unsigned u = __float_as_uint(gate[i]);
    const bool ok = (pass == 0) || ((u >> (shift + 8)) == pref);
    if (ok) atomicAdd(&lh[(u >> shift) & 255u], 1u);
  }
  __syncthreads();
  const unsigned c = lh[threadIdx.x];
  if (c) atomicAdd(&hist[pass*256 + threadIdx.x], c);
}

__global__ void tk_pick(const unsigned* __restrict__ hist, int* __restrict__ st, int pass)
{
  if (threadIdx.x != 0) return;
  const unsigned pref = (unsigned)st[0];
  int kk = st[1];
  const unsigned* h = hist + pass*256;
  int cum = 0, b = 255;
  for (; b >= 0; --b) {
    const int c = (int)h[b];
    if (cum + c >= kk) break;
    cum += c;
  }
  if (b < 0) b = 0;
  st[0] = (int)((pref << 8) | (unsigned)b);
  st[1] = kk - cum;
}

__global__ void __launch_bounds__(256) tk_compact(
    const float* __restrict__ gate, const int* __restrict__ st,
    int* __restrict__ sel, int* __restrict__ cnt, int* __restrict__ eqbuf)
{
  const unsigned T = (unsigned)st[0];
  for (int i = blockIdx.x*256 + threadIdx.x; i < LL; i += gridDim.x*256) {
    const unsigned u = __float_as_uint(gate[i]);
    if (u > T) {
      const int p = atomicAdd(&cnt[0], 1);
      sel[p] = i;
    } else if (u == T) {
      const int p = atomicAdd(&cnt[1], 1);
      if (p < EQCAP) eqbuf[p] = i;
    }
  }
}

__global__ void __launch_bounds__(1024) tk_fin(
    int* __restrict__ sel, const int* __restrict__ cnt, const int* __restrict__ eqbuf)
{
  const int g = cnt[0];
  const int need = KSEL - g;
  int M = cnt[1]; if (M > EQCAP) M = EQCAP;
  for (int x = threadIdx.x; x < M; x += 1024) {
    const int v = eqbuf[x];
    int rank = 0;
    for (int j = 0; j < M; ++j) rank += (eqbuf[j] < v);
    if (rank < need) sel[g + rank] = v;
  }
}

// ---------------------------------------------------------------------------
__global__ void __launch_bounds__(256) transpose_kernel(
    const float* __restrict__ in, float* __restrict__ out, int R, int Ck)
{
  __shared__ float t[32][33];
  const int bx = blockIdx.x*32, by = blockIdx.y*32;
  const int x = threadIdx.x & 31, y4 = threadIdx.x >> 5;
  #pragma unroll
  for (int i = 0; i < 4; ++i) {
    int r = by + y4 + i*8, c = bx + x;
    t[y4 + i*8][x] = (r < R && c < Ck) ? in[r*Ck + c] : 0.f;
  }
  __syncthreads();
  #pragma unroll
  for (int i = 0; i < 4; ++i) {
    int c = bx + y4 + i*8, r = by + x;
    if (c < Ck && r < R) out[c*R + r] = t[x][y4 + i*8];
  }
}

// ---------------------------------------------------------------------------
// Gather: q from down (C,L); kv from final split buffer (res 256, padded 258).
// ---------------------------------------------------------------------------
__global__ void __launch_bounds__(256) gather_kernel(
    const float* __restrict__ down, const u16* __restrict__ xf,
    const int* __restrict__ sel, float* __restrict__ q_in, float* __restrict__ kv_in)
{
  const int n = blockIdx.x, c = threadIdx.x;
  const int l = sel[n];
  q_in[n*256 + c] = down[c*LL + l];
  const int pr = (l >> 8) + 1, pc = (l & 255) + 1;
  const size_t PS = (size_t)258*258*32;
  const size_t o = (size_t)(c >> 5)*PS + ((size_t)(pr*258 + pc))*32 + (c & 31);
  kv_in[n*256 + c] = bf2f(xf[o]) + bf2f(xf[o + (size_t)8*PS]);
}

// ---------------------------------------------------------------------------
__global__ void __launch_bounds__(256) rowgemm_kernel(
    const float* __restrict__ WT, int wld,
    const float* __restrict__ srcA, const float* __restrict__ srcB,
    const float* __restrict__ bias, float* __restrict__ out, int N)
{
  const int g = blockIdx.y;
  const int tid = threadIdx.x;
  const int co = g*256 + tid;
  const float* src = (g == 0) ? srcA : srcB;
  float* outg = out + (size_t)g*(KSEL*256);
  __shared__ float Bl[16][256];
  const int n0 = blockIdx.x*16;
  #pragma unroll
  for (int j = 0; j < 16; ++j) {
    int n = n0 + j;
    Bl[j][tid] = (n < N) ? src[n*256 + tid] : 0.f;
  }
  __syncthreads();
  float acc[16];
  const float bv = bias[co];
  #pragma unroll
  for (int j = 0; j < 16; ++j) acc[j] = bv;
  #pragma unroll 4
  for (int ci = 0; ci < 256; ++ci) {
    const float w = WT[ci*wld + co];
    #pragma unroll
    for (int j = 0; j < 16; ++j) acc[j] += Bl[j][ci]*w;
  }
  #pragma unroll
  for (int j = 0; j < 16; ++j) {
    int n = n0 + j;
    if (n < N) outg[n*256 + tid] = acc[j];
  }
}

// ---------------------------------------------------------------------------
__global__ void __launch_bounds__(256) attn_kernel(
    const float* __restrict__ qb, const float* __restrict__ kb,
    const float* __restrict__ vb, float* __restrict__ ctx)
{
  const int n = blockIdx.x, h = blockIdx.y;
  const int tid = threadIdx.x;
  __shared__ float sc[KSEL];
  __shared__ float qv[32];
  __shared__ float red[4];
  __shared__ float part[8][32];
  __shared__ float s_mx, s_sum;

  if (tid < 32) qv[tid] = qb[n*256 + h*32 + tid];
  __syncthreads();

  const float scale = 0.17677669529663687f;
  for (int m = tid; m < KSEL; m += 256) {
    const float* kr = kb + m*256 + h*32;
    float s = 0.f;
    #pragma unroll
    for (int d = 0; d < 32; ++d) s += qv[d]*kr[d];
    sc[m] = s*scale;
  }
  __syncthreads();

  float lm = -1e30f;
  for (int m = tid; m < KSEL; m += 256) lm = fmaxf(lm, sc[m]);
  #pragma unroll
  for (int off = 32; off > 0; off >>= 1) lm = fmaxf(lm, __shfl_down(lm, off));
  if ((tid & 63) == 0) red[tid >> 6] = lm;
  __syncthreads();
  if (tid == 0) s_mx = fmaxf(fmaxf(red[0], red[1]), fmaxf(red[2], red[3]));
  __syncthreads();
  const float mx = s_mx;

  float ls = 0.f;
  for (int m = tid; m < KSEL; m += 256) {
    float pv = expf(sc[m] - mx);
    sc[m] = pv;
    ls += pv;
  }
  #pragma unroll
  for (int off = 32; off > 0; off >>= 1) ls += __shfl_down(ls, off);
  if ((tid & 63) == 0) red[tid >> 6] = ls;
  __syncthreads();
  if (tid == 0) s_sum = red[0]+red[1]+red[2]+red[3];
  __syncthreads();

  const int d = tid & 31, g = tid >> 5;
  float a = 0.f;
  for (int m = g; m < KSEL; m += 8) a += sc[m]*vb[m*256 + h*32 + d];
  part[g][d] = a;
  __syncthreads();
  if (tid < 32) {
    float s = 0.f;
    #pragma unroll
    for (int gg = 0; gg < 8; ++gg) s += part[gg][tid];
    ctx[n*256 + h*32 + tid] = s / s_sum;
  }
}

// ---------------------------------------------------------------------------
__global__ void __launch_bounds__(256) copy_kernel(
    const float4* __restrict__ src, float4* __restrict__ dst)
{
  const int i = blockIdx.x*256 + threadIdx.x;
  dst[i] = src[i];
}

__global__ void __launch_bounds__(256) scatter_kernel(
    const float* __restrict__ down, const float* __restrict__ gate,
    const int* __restrict__ sel, const float* __restrict__ att,
    float* __restrict__ out)
{
  const int n = blockIdx.x, c = threadIdx.x;
  const int l = sel[n];
  const float g = gate[l];
  const float dv = down[c*LL + l];
  out[c*LL + l] = g*att[n*256 + c] + (1.f - g)*dv;
}

// ---------------------------------------------------------------------------
extern "C" void kernel_launch(void* const* d_in, const int* in_sizes, int n_in,
                              void* d_out, int out_size, void* d_ws, size_t ws_size,
                              hipStream_t stream)
{
  (void)in_sizes; (void)n_in; (void)out_size; (void)ws_size;
  const float* down   = (const float*)d_in[0];
  const float* swinT  = (const float*)d_in[1];
  const float* wt_w   = (const float*)d_in[2];
  const float* wt_b   = (const float*)d_in[3];
  const float* ct_w   = (const float*)d_in[4];
  const float* ct_b   = (const float*)d_in[5];
  const float* up_w   = (const float*)d_in[6];
  const float* up_b   = (const float*)d_in[7];
  const float* gate_w = (const float*)d_in[8];
  const float* gate_b = (const float*)d_in[9];
  const float* ipw    = (const float*)d_in[10];
  const float* ipb    = (const float*)d_in[11];
  const float* ow     = (const float*)d_in[12];
  const float* ob     = (const float*)d_in[13];
  float* out = (float*)d_out;

  char* wsp = (char*)d_ws;
  size_t off = 0;
  auto take = [&](size_t bytes) -> void* {
    void* r = wsp + off;
    off += (bytes + 255) & ~(size_t)255;
    return r;
  };
  u16*      A     = (u16*)     take((size_t)16*258*258*32*sizeof(u16)); // 68.2 MB
  u16*      B     = (u16*)     take((size_t)16*258*258*32*sizeof(u16)); // 68.2 MB
  u16*      W3    = (u16*)     take((size_t)5898240*sizeof(u16));       // 11.8 MB
  u16*      W4    = (u16*)     take((size_t)10485760*sizeof(u16));      // 21.0 MB
  float*    gateb = (float*)   take((size_t)LL*sizeof(float));
  int*      sel   = (int*)     take(4096);
  unsigned* hist  = (unsigned*)take(4*256*sizeof(unsigned));
  int*      st    = (int*)     take(256);
  int*      cnt   = (int*)     take(256);
  int*      eqbuf = (int*)     take((size_t)EQCAP*sizeof(int));
  float*    WT    = (float*)   take((size_t)768*256*sizeof(float));
  float*    OWT   = (float*)   take((size_t)256*256*sizeof(float));
  float*    q_in  = (float*)   take((size_t)KSEL*256*sizeof(float));
  float*    kv_in = (float*)   take((size_t)KSEL*256*sizeof(float));
  float*    qkv   = (float*)   take((size_t)3*KSEL*256*sizeof(float));
  float*    ctx   = (float*)   take((size_t)KSEL*256*sizeof(float));
  float*    att   = (float*)   take((size_t)KSEL*256*sizeof(float));

  // ---- weight prep ----
  prep_w3_kernel<<<(5898240 + 255)/256, 256, 0, stream>>>(up_w, W3);
  prep_wt_kernel<<<(10485760 + 255)/256, 256, 0, stream>>>(ct_w, W4);

  // ---- decoder pipeline ----
  auto zbBlocks = [](int H) { return (16*(4*(H+2) - 4)*32 + 255)/256; };
  zb2_kernel<<<zbBlocks(8), 256, 0, stream>>>(A, 8);
  conv1x1_kernel<<<256, 64, 0, stream>>>(swinT, wt_w, wt_b, A);
  int r = 8;
  for (int s = 0; s < 5; ++s) {
    const int o = 2*r;
    const int tI = (r + 15)/16, tO = o/16;
    zb2_kernel<<<zbBlocks(o), 256, 0, stream>>>(B, o);
    convt_mfma<<<dim3(tI, tI, 16), 256, 0, stream>>>(
        A, W4 + (size_t)s*2*16*65536, ct_b + s*256, B, r);
    zb2_kernel<<<zbBlocks(o), 256, 0, stream>>>(A, o);
    conv3_mfma<<<dim3(tO, tO, 4), 256, 0, stream>>>(
        B, W3 + (size_t)s*2*9*65536, up_b + s*256, A, o);
    r = o;
  }

  // ---- gate + top-k ----
  gate_kernel<<<256, 256, 0, stream>>>(down, gate_w, gate_b, gateb);
  tk_zero<<<1, 1024, 0, stream>>>(hist, st, cnt);
  for (int p = 0; p < 4; ++p) {
    tk_hist<<<256, 256, 0, stream>>>(gateb, st, hist, p);
    tk_pick<<<1, 64, 0, stream>>>(hist, st, p);
  }
  tk_compact<<<256, 256, 0, stream>>>(gateb, st, sel, cnt, eqbuf);
  tk_fin<<<1, 1024, 0, stream>>>(sel, cnt, eqbuf);

  // ---- attention ----
  transpose_kernel<<<dim3(8, 24), 256, 0, stream>>>(ipw, WT, 768, 256);
  transpose_kernel<<<dim3(8, 8), 256, 0, stream>>>(ow, OWT, 256, 256);
  gather_kernel<<<KSEL, 256, 0, stream>>>(down, A, sel, q_in, kv_in);
  rowgemm_kernel<<<dim3(41, 3), 256, 0, stream>>>(WT, 768, q_in, kv_in, ipb, qkv, KSEL);
  attn_kernel<<<dim3(KSEL, 8), 256, 0, stream>>>(qkv, qkv + KSEL*256, qkv + 2*KSEL*256, ctx);
  rowgemm_kernel<<<dim3(41, 1), 256, 0, stream>>>(OWT, 256, ctx, ctx, ob, att, KSEL);

  // ---- output: copy down, then blend the selected pixels ----
  copy_kernel<<<16384, 256, 0, stream>>>((const float4*)down, (float4*)out);
  scatter_kernel<<<KSEL, 256, 0, stream>>>(down, gateb, sel, att, out);
}

// Round 5
// 1325.623 us; speedup vs baseline: 6.0576x; 1.1153x over previous
//
#include <hip/hip_runtime.h>

#define LL 65536      // H*W
#define KSEL 655      // top-k count
#define TPAD 36       // LDS per-pixel stride in u16 (32 data + 4 pad)
#define EQCAP 8192

typedef unsigned short u16;
typedef __attribute__((ext_vector_type(8))) short s16x8;
typedef __attribute__((ext_vector_type(4))) float f32x4;

__device__ __forceinline__ u16 f2bf(float v) {
  unsigned u = __float_as_uint(v);
  u += 0x7FFFu + ((u >> 16) & 1u);
  return (u16)(u >> 16);
}
__device__ __forceinline__ float bf2f(u16 h) {
  return __uint_as_float(((unsigned)h) << 16);
}

// ---------------------------------------------------------------------------
// Zero the borders of a padded split-activation buffer:
// layout [16 planes (g=0..7 hi, 8..15 lo)][(H+2)][(W+2)][32ci].
// ---------------------------------------------------------------------------
__global__ void zb2_kernel(u16* __restrict__ buf, int H)
{
  const int H2 = H + 2;
  const int PS = H2*H2*32;
  const int per = (4*H2 - 4)*32;
  const int tot = 16*per;
  for (int t = blockIdx.x*blockDim.x + threadIdx.x; t < tot; t += gridDim.x*blockDim.x) {
    const int pl = t / per, e = t - pl*per;
    const int pix = e >> 5, cw = e & 31;
    int y, x;
    if (pix < H2)        { y = 0;      x = pix; }
    else if (pix < 2*H2) { y = H2-1;   x = pix - H2; }
    else { int k2 = pix - 2*H2; y = 1 + (k2 >> 1); x = (k2 & 1) ? (H2-1) : 0; }
    buf[(size_t)pl*PS + ((size_t)(y*H2 + x))*32 + cw] = 0;
  }
}

// ---------------------------------------------------------------------------
// Weight prep conv3x3 (LDS-tiled transpose, coalesced both sides).
// up_w (5, co256, ci256, 3,3) fp32 ->
// W3 flat: (((((s*2+hl)*9+tap)*4+cob)*4+n)*8+ch)*512 + lane*8 + e
//   co = cob*64+n*16+(lane&15), ci = ch*32+(lane>>4)*8+e.
// grid: 5*16*4 = 320 blocks (s, ciq of 16 ci, cob), 256 threads.
// ---------------------------------------------------------------------------
__global__ void __launch_bounds__(256) prep_w3_kernel(
    const float* __restrict__ up_w, u16* __restrict__ W3)
{
  const int b = blockIdx.x;
  const int cob = b & 3, ciq = (b >> 2) & 15, s = b >> 6;
  const int ci0 = ciq*16, ch = ciq >> 1, k0 = (ciq & 1)*2;
  const int tid = threadIdx.x;
  __shared__ float lds[64*145];

  // load: up_w[s][cob*64+co][ci0..ci0+16][0..9] = 144 contiguous floats per co
  for (int t = tid; t < 64*144; t += 256) {
    const int co_l = t / 144, r = t - co_l*144;
    lds[co_l*145 + r] = up_w[((size_t)((s*256 + cob*64 + co_l)*256 + ci0))*9 + r];
  }
  __syncthreads();

  // store: per (hl,tap,n): 256 contiguous u16 at offset k0*128
  for (int u = tid; u < 18432; u += 256) {
    const int within = u & 255, combo = u >> 8;
    const int n = combo & 3, c2 = combo >> 2;
    const int tap = c2 % 9, hl = c2 / 9;
    const int lane_loc = within >> 3, e = within & 7;
    const int lx = lane_loc & 15, kgl = lane_loc >> 4;
    const int co_l = n*16 + lx, ci_l = kgl*8 + e;
    const float v = lds[co_l*145 + ci_l*9 + tap];
    const u16 h = f2bf(v);
    const u16 val = hl ? f2bf(v - bf2f(h)) : h;
    const size_t addr = ((size_t)(((((s*2 + hl)*9 + tap)*4 + cob)*4 + n)*8 + ch))*512
                      + k0*128 + within;
    W3[addr] = val;
  }
}

// ---------------------------------------------------------------------------
// Weight prep convT (LDS-tiled transpose).
// ct_w (5, ci256, co256, 4,4) fp32 ->
// W4 flat: (((((s*2+hl)*16+pdt)*4+cob)*4+n)*8+ch)*512 + lane*8 + e
// pdt=p*4+dt; ky=3-py-2dy, kx=3-px-2dx.
// grid: 5*32*4 = 640 blocks (s, ciq of 8 ci, cob), 256 threads.
// LDS layout: lds[ci_l*1089 + co_l*17 + tap]  (pad stride 17 per co).
// ---------------------------------------------------------------------------
__global__ void __launch_bounds__(256) prep_wt_kernel(
    const float* __restrict__ ct_w, u16* __restrict__ W4)
{
  const int b = blockIdx.x;
  const int cob = b & 3, ciq = (b >> 2) & 31, s = b >> 7;
  const int ci0 = ciq*8, ch = ciq >> 2, kg = ciq & 3;
  const int tid = threadIdx.x;
  __shared__ float lds[8*1089];

  // load: ct_w[s][ci0+ci][cob*64 .. +64][0..16] = 1024 contiguous floats per ci.
  // Write into LDS pre-padded: per-co stride 17 (r>>4 = co_l, r&15 = tap).
  for (int t = tid; t < 8192; t += 256) {
    const int ci_l = t >> 10, r = t & 1023;
    lds[ci_l*1089 + (r >> 4)*17 + (r & 15)] =
        ct_w[((size_t)((s*256 + ci0 + ci_l)*256 + cob*64))*16 + r];
  }
  __syncthreads();

  // store: per (hl,pdt,n): 128 contiguous u16 at offset kg*128
  for (int u = tid; u < 16384; u += 256) {
    const int within = u & 127, combo = u >> 7;
    const int n = combo & 3, pdt = (combo >> 2) & 15, hl = combo >> 6;
    const int lx = within >> 3, e = within & 7;
    const int p = pdt >> 2, dt = pdt & 3;
    const int py = p >> 1, px = p & 1, dy = dt >> 1, dx = dt & 1;
    const int ky = 3 - py - 2*dy, kx = 3 - px - 2*dx;
    const float v = lds[e*1089 + (n*16 + lx)*17 + ky*4 + kx];
    const u16 h = f2bf(v);
    const u16 val = hl ? f2bf(v - bf2f(h)) : h;
    const size_t addr = ((size_t)(((((s*2 + hl)*16 + pdt)*4 + cob)*4 + n)*8 + ch))*512
                      + kg*128 + within;
    W4[addr] = val;
  }
}

// ---------------------------------------------------------------------------
// 1x1 conv: swinT (768,8,8) -> split activation buffer at res 8 (padded 10).
// ---------------------------------------------------------------------------
__global__ void __launch_bounds__(64) conv1x1_kernel(
    const float* __restrict__ swinT, const float* __restrict__ w,
    const float* __restrict__ b, u16* __restrict__ out)
{
  const int co = blockIdx.x, pp = threadIdx.x;
  float acc = b[co];
  for (int ci = 0; ci < 768; ++ci)
    acc += swinT[ci*64 + pp] * w[co*768 + ci];
  const int py = pp >> 3, px = pp & 7;
  const int g = co >> 5, cw = co & 31;
  const size_t o = (size_t)g*3200 + ((size_t)((py+1)*10 + px+1))*32 + cw;
  const u16 h = f2bf(acc);
  out[o] = h;
  out[o + (size_t)8*3200] = f2bf(acc - bf2f(h));
}

// ---------------------------------------------------------------------------
// Stage ROWSx18 pixel tile x 32 ci (hi+lo) into LDS (padded pixel stride).
// ---------------------------------------------------------------------------
template<int ROWS>
__device__ __forceinline__ void stage_tile(
    const u16* __restrict__ in, u16* __restrict__ tile,
    int ch, int PS, int H2, int Y0, int X0, int tid)
{
  const int PIX = ROWS*18;
  for (int t = tid; t < 2*PIX*4; t += 256) {
    const int which = (t >= PIX*4) ? 1 : 0;
    const int e = which ? t - PIX*4 : t;
    const int p = e >> 2, c8 = e & 3;
    const int r = p / 18, c = p - r*18;
    const int gr = Y0 + r, gc = X0 + c;
    s16x8 v = {};
    if (gr < H2 && gc < H2)
      v = *(const s16x8*)&in[(size_t)(which*8 + ch)*PS + ((size_t)(gr*H2 + gc))*32 + c8*8];
    *(s16x8*)&tile[which*(PIX*TPAD) + p*TPAD + c8*8] = v;
  }
}

// ---------------------------------------------------------------------------
// conv3x3 via MFMA (split bf16). Weights are the A operand -> D maps co to
// regs (row = kg*4+j), x to lanes (col = lane&15); epilogue stores ushort4.
// grid (H/16, H/(4*MI), 4 co-blocks of 64), block 256.
// ---------------------------------------------------------------------------
template<int MI>
__global__ void __launch_bounds__(256, 2) conv3_mfma(
    const u16* __restrict__ in, const u16* __restrict__ W,
    const float* __restrict__ bias, u16* __restrict__ out, int H)
{
  const int ROWS = 4*MI + 2;
  const int TILE_H = ROWS*18*TPAD;
  const int H2 = H + 2;
  const int PS = H2*H2*32;
  const int tid = threadIdx.x;
  const int lane = tid & 63, wv = tid >> 6;
  const int lx = lane & 15, kg = lane >> 4;
  const int X0 = blockIdx.x*16, Y0 = blockIdx.y*(4*MI);
  const int cob = blockIdx.z;
  const int yl0 = wv*MI;

  __shared__ u16 tile[2*(4*MI+2)*18*TPAD];
  f32x4 acc[MI][4] = {};
  const u16* Wl = W + lane*8;

  for (int ch = 0; ch < 8; ++ch) {
    stage_tile<ROWS>(in, tile, ch, PS, H2, Y0, X0, tid);
    __syncthreads();
    #pragma unroll
    for (int dxg = 0; dxg < 3; ++dxg) {
      s16x8 ah[MI+2], al[MI+2];
      #pragma unroll
      for (int r = 0; r < MI+2; ++r) {
        const int ad = ((yl0 + r)*18 + lx + dxg)*TPAD + kg*8;
        ah[r] = *(const s16x8*)&tile[ad];
        al[r] = *(const s16x8*)&tile[TILE_H + ad];
      }
      #pragma unroll
      for (int dy = 0; dy < 3; ++dy) {
        const int tap = dy*3 + dxg;
        s16x8 bh[4], bl[4];
        #pragma unroll
        for (int n = 0; n < 4; ++n) {
          const int oh = (((tap*4 + cob)*4 + n)*8 + ch)*512;
          bh[n] = *(const s16x8*)&Wl[oh];
          bl[n] = *(const s16x8*)&Wl[oh + 589824];   // hl stride = 9*65536
        }
        #pragma unroll
        for (int mi = 0; mi < MI; ++mi)
          #pragma unroll
          for (int n = 0; n < 4; ++n) {
            acc[mi][n] = __builtin_amdgcn_mfma_f32_16x16x32_bf16(bh[n], ah[mi+dy], acc[mi][n], 0, 0, 0);
            acc[mi][n] = __builtin_amdgcn_mfma_f32_16x16x32_bf16(bl[n], ah[mi+dy], acc[mi][n], 0, 0, 0);
            acc[mi][n] = __builtin_amdgcn_mfma_f32_16x16x32_bf16(bh[n], al[mi+dy], acc[mi][n], 0, 0, 0);
          }
      }
    }
    __syncthreads();
  }

  // D mapping: col(lane&15)=x, row(kg*4+j)=co within n-block.
  const int x = X0 + lx;
  #pragma unroll
  for (int n = 0; n < 4; ++n) {
    const int co0 = cob*64 + n*16 + kg*4;
    const float4 bv = *(const float4*)&bias[co0];
    const int g = co0 >> 5, cw = co0 & 31;
    #pragma unroll
    for (int mi = 0; mi < MI; ++mi) {
      const int y = Y0 + yl0 + mi;
      const float v0 = acc[mi][n][0] + bv.x;
      const float v1 = acc[mi][n][1] + bv.y;
      const float v2 = acc[mi][n][2] + bv.z;
      const float v3 = acc[mi][n][3] + bv.w;
      const u16 h0 = f2bf(v0), h1 = f2bf(v1), h2 = f2bf(v2), h3 = f2bf(v3);
      const size_t o = (size_t)g*PS + ((size_t)((y+1)*H2 + x+1))*32 + cw;
      *(ushort4*)&out[o] = make_ushort4(h0, h1, h2, h3);
      *(ushort4*)&out[o + (size_t)8*PS] = make_ushort4(
          f2bf(v0 - bf2f(h0)), f2bf(v1 - bf2f(h1)),
          f2bf(v2 - bf2f(h2)), f2bf(v3 - bf2f(h3)));
    }
  }
}

// ---------------------------------------------------------------------------
// ConvTranspose2d k4 s2 p1 + ReLU via MFMA (split bf16), parity-decomposed.
// grid (ceil(Hin/16), Hin/(4*MI), 16: z = parity*4 + co-block), block 256.
// ---------------------------------------------------------------------------
template<int MI>
__global__ void __launch_bounds__(256, 2) convt_mfma(
    const u16* __restrict__ in, const u16* __restrict__ W,
    const float* __restrict__ bias, u16* __restrict__ out, int Hin)
{
  const int ROWS = 4*MI + 2;
  const int TILE_H = ROWS*18*TPAD;
  const int Hout = Hin*2;
  const int H2i = Hin + 2, H2o = Hout + 2;
  const int PSi = H2i*H2i*32, PSo = H2o*H2o*32;
  const int tid = threadIdx.x;
  const int lane = tid & 63, wv = tid >> 6;
  const int lx = lane & 15, kg = lane >> 4;
  const int X0 = blockIdx.x*16, Y0 = blockIdx.y*(4*MI);
  const int p = blockIdx.z >> 2, cob = blockIdx.z & 3;
  const int py = p >> 1, px = p & 1;
  const int yl0 = wv*MI;

  __shared__ u16 tile[2*(4*MI+2)*18*TPAD];
  f32x4 acc[MI][4] = {};
  const u16* Wl = W + lane*8;

  for (int ch = 0; ch < 8; ++ch) {
    stage_tile<ROWS>(in, tile, ch, PSi, H2i, Y0, X0, tid);
    __syncthreads();
    #pragma unroll
    for (int dxg = 0; dxg < 2; ++dxg) {
      s16x8 ah[MI+1], al[MI+1];
      #pragma unroll
      for (int r = 0; r < MI+1; ++r) {
        const int ad = ((yl0 + r + py)*18 + lx + px + dxg)*TPAD + kg*8;
        ah[r] = *(const s16x8*)&tile[ad];
        al[r] = *(const s16x8*)&tile[TILE_H + ad];
      }
      #pragma unroll
      for (int dy = 0; dy < 2; ++dy) {
        const int pdt = p*4 + dy*2 + dxg;
        s16x8 bh[4], bl[4];
        #pragma unroll
        for (int n = 0; n < 4; ++n) {
          const int oh = (((pdt*4 + cob)*4 + n)*8 + ch)*512;
          bh[n] = *(const s16x8*)&Wl[oh];
          bl[n] = *(const s16x8*)&Wl[oh + 1048576];  // hl stride = 16*65536
        }
        #pragma unroll
        for (int mi = 0; mi < MI; ++mi)
          #pragma unroll
          for (int n = 0; n < 4; ++n) {
            acc[mi][n] = __builtin_amdgcn_mfma_f32_16x16x32_bf16(bh[n], ah[mi+dy], acc[mi][n], 0, 0, 0);
            acc[mi][n] = __builtin_amdgcn_mfma_f32_16x16x32_bf16(bl[n], ah[mi+dy], acc[mi][n], 0, 0, 0);
            acc[mi][n] = __builtin_amdgcn_mfma_f32_16x16x32_bf16(bh[n], al[mi+dy], acc[mi][n], 0, 0, 0);
          }
      }
    }
    __syncthreads();
  }

  const int xi = X0 + lx;
  if (xi < Hin) {
    const int X = 2*xi + px;
    #pragma unroll
    for (int n = 0; n < 4; ++n) {
      const int co0 = cob*64 + n*16 + kg*4;
      const float4 bv = *(const float4*)&bias[co0];
      const int g = co0 >> 5, cw = co0 & 31;
      #pragma unroll
      for (int mi = 0; mi < MI; ++mi) {
        const int Y = 2*(Y0 + yl0 + mi) + py;
        const float v0 = fmaxf(acc[mi][n][0] + bv.x, 0.f);
        const float v1 = fmaxf(acc[mi][n][1] + bv.y, 0.f);
        const float v2 = fmaxf(acc[mi][n][2] + bv.z, 0.f);
        const float v3 = fmaxf(acc[mi][n][3] + bv.w, 0.f);
        const u16 h0 = f2bf(v0), h1 = f2bf(v1), h2 = f2bf(v2), h3 = f2bf(v3);
        const size_t o = (size_t)g*PSo + ((size_t)((Y+1)*H2o + X+1))*32 + cw;
        *(ushort4*)&out[o] = make_ushort4(h0, h1, h2, h3);
        *(ushort4*)&out[o + (size_t)8*PSo] = make_ushort4(
            f2bf(v0 - bf2f(h0)), f2bf(v1 - bf2f(h1)),
            f2bf(v2 - bf2f(h2)), f2bf(v3 - bf2f(h3)));
      }
    }
  }
}

// ---------------------------------------------------------------------------
// gate[l] = sigmoid(sum_c down[c*L+l]*gw[c] + gb)
// ---------------------------------------------------------------------------
__global__ void __launch_bounds__(256) gate_kernel(
    const float* __restrict__ down, const float* __restrict__ gw,
    const float* __restrict__ gb, float* __restrict__ gate)
{
  const int l = blockIdx.x*256 + threadIdx.x;
  float a0 = 0.f, a1 = 0.f, a2 = 0.f, a3 = 0.f;
  for (int c = 0; c < 256; c += 4) {
    a0 += down[(c+0)*LL + l] * gw[c+0];
    a1 += down[(c+1)*LL + l] * gw[c+1];
    a2 += down[(c+2)*LL + l] * gw[c+2];
    a3 += down[(c+3)*LL + l] * gw[c+3];
  }
  const float a = (a0+a1) + (a2+a3) + gb[0];
  gate[l] = 1.f / (1.f + expf(-a));
}

// ---------------------------------------------------------------------------
// Grid-wide exact top-K radix select (set semantics; ties -> lowest index).
// ---------------------------------------------------------------------------
__global__ void tk_zero(unsigned* __restrict__ hist, int* __restrict__ st, int* __restrict__ cnt)
{
  const int t = threadIdx.x;
  if (t < 1024) hist[t] = 0;
  if (t == 0) { st[0] = 0; st[1] = KSEL; cnt[0] = 0; cnt[1] = 0; }
}

__global__ void __launch_bounds__(256) tk_hist(
    const float* __restrict__ gate, const int* __restrict__ st,
    unsigned* __restrict__ hist, int pass)
{
  __shared__ unsigned lh[256];
  lh[threadIdx.x] = 0;
  __syncthreads();
  const unsigned pref = (unsigned)st[0];
  const int shift = 24 - 8*pass;
  for (int i = blockIdx.x*256 + threadIdx.x; i < LL; i += gridDim.x*256) {
    const unsigned u = __float_as_uint(gate[i]);
    const bool ok = (pass == 0) || ((u >> (shift + 8)) == pref);
    if (ok) atomicAdd(&lh[(u >> shift) & 255u], 1u);
  }
  __syncthreads();
  const unsigned c = lh[threadIdx.x];
  if (c) atomicAdd(&hist[pass*256 + threadIdx.x], c);
}

__global__ void tk_pick(const unsigned* __restrict__ hist, int* __restrict__ st, int pass)
{
  if (threadIdx.x != 0) return;
  const unsigned pref = (unsigned)st[0];
  int kk = st[1];
  const unsigned* h = hist + pass*256;
  int cum = 0, b = 255;
  for (; b >= 0; --b) {
    const int c = (int)h[b];
    if (cum + c >= kk) break;
    cum += c;
  }
  if (b < 0) b = 0;
  st[0] = (int)((pref << 8) | (unsigned)b);
  st[1] = kk - cum;
}

__global__ void __launch_bounds__(256) tk_compact(
    const float* __restrict__ gate, const int* __restrict__ st,
    int* __restrict__ sel, int* __restrict__ cnt, int* __restrict__ eqbuf)
{
  const unsigned T = (unsigned)st[0];
  for (int i = blockIdx.x*256 + threadIdx.x; i < LL; i += gridDim.x*256) {
    const unsigned u = __float_as_uint(gate[i]);
    if (u > T) {
      const int p = atomicAdd(&cnt[0], 1);
      sel[p] = i;
    } else if (u == T) {
      const int p = atomicAdd(&cnt[1], 1);
      if (p < EQCAP) eqbuf[p] = i;
    }
  }
}

__global__ void __launch_bounds__(1024) tk_fin(
    int* __restrict__ sel, const int* __restrict__ cnt, const int* __restrict__ eqbuf)
{
  const int g = cnt[0];
  const int need = KSEL - g;
  int M = cnt[1]; if (M > EQCAP) M = EQCAP;
  for (int x = threadIdx.x; x < M; x += 1024) {
    const int v = eqbuf[x];
    int rank = 0;
    for (int j = 0; j < M; ++j) rank += (eqbuf[j] < v);
    if (rank < need) sel[g + rank] = v;
  }
}

// ---------------------------------------------------------------------------
__global__ void __launch_bounds__(256) transpose_kernel(
    const float* __restrict__ in, float* __restrict__ out, int R, int Ck)
{
  __shared__ float t[32][33];
  const int bx = blockIdx.x*32, by = blockIdx.y*32;
  const int x = threadIdx.x & 31, y4 = threadIdx.x >> 5;
  #pragma unroll
  for (int i = 0; i < 4; ++i) {
    int r = by + y4 + i*8, c = bx + x;
    t[y4 + i*8][x] = (r < R && c < Ck) ? in[r*Ck + c] : 0.f;
  }
  __syncthreads();
  #pragma unroll
  for (int i = 0; i < 4; ++i) {
    int c = bx + y4 + i*8, r = by + x;
    if (c < Ck && r < R) out[c*R + r] = t[x][y4 + i*8];
  }
}

// ---------------------------------------------------------------------------
// Gather: q from down (C,L); kv from final split buffer (res 256, padded 258).
// ---------------------------------------------------------------------------
__global__ void __launch_bounds__(256) gather_kernel(
    const float* __restrict__ down, const u16* __restrict__ xf,
    const int* __restrict__ sel, float* __restrict__ q_in, float* __restrict__ kv_in)
{
  const int n = blockIdx.x, c = threadIdx.x;
  const int l = sel[n];
  q_in[n*256 + c] = down[c*LL + l];
  const int pr = (l >> 8) + 1, pc = (l & 255) + 1;
  const size_t PS = (size_t)258*258*32;
  const size_t o = (size_t)(c >> 5)*PS + ((size_t)(pr*258 + pc))*32 + (c & 31);
  kv_in[n*256 + c] = bf2f(xf[o]) + bf2f(xf[o + (size_t)8*PS]);
}

// ---------------------------------------------------------------------------
__global__ void __launch_bounds__(256) rowgemm_kernel(
    const float* __restrict__ WT, int wld,
    const float* __restrict__ srcA, const float* __restrict__ srcB,
    const float* __restrict__ bias, float* __restrict__ out, int N)
{
  const int g = blockIdx.y;
  const int tid = threadIdx.x;
  const int co = g*256 + tid;
  const float* src = (g == 0) ? srcA : srcB;
  float* outg = out + (size_t)g*(KSEL*256);
  __shared__ float Bl[16][256];
  const int n0 = blockIdx.x*16;
  #pragma unroll
  for (int j = 0; j < 16; ++j) {
    int n = n0 + j;
    Bl[j][tid] = (n < N) ? src[n*256 + tid] : 0.f;
  }
  __syncthreads();
  float acc[16];
  const float bv = bias[co];
  #pragma unroll
  for (int j = 0; j < 16; ++j) acc[j] = bv;
  #pragma unroll 4
  for (int ci = 0; ci < 256; ++ci) {
    const float w = WT[ci*wld + co];
    #pragma unroll
    for (int j = 0; j < 16; ++j) acc[j] += Bl[j][ci]*w;
  }
  #pragma unroll
  for (int j = 0; j < 16; ++j) {
    int n = n0 + j;
    if (n < N) outg[n*256 + tid] = acc[j];
  }
}

// ---------------------------------------------------------------------------
__global__ void __launch_bounds__(256) attn_kernel(
    const float* __restrict__ qb, const float* __restrict__ kb,
    const float* __restrict__ vb, float* __restrict__ ctx)
{
  const int n = blockIdx.x, h = blockIdx.y;
  const int tid = threadIdx.x;
  __shared__ float sc[KSEL];
  __shared__ float qv[32];
  __shared__ float red[4];
  __shared__ float part[8][32];
  __shared__ float s_mx, s_sum;

  if (tid < 32) qv[tid] = qb[n*256 + h*32 + tid];
  __syncthreads();

  const float scale = 0.17677669529663687f;
  for (int m = tid; m < KSEL; m += 256) {
    const float* kr = kb + m*256 + h*32;
    float s = 0.f;
    #pragma unroll
    for (int d = 0; d < 32; ++d) s += qv[d]*kr[d];
    sc[m] = s*scale;
  }
  __syncthreads();

  float lm = -1e30f;
  for (int m = tid; m < KSEL; m += 256) lm = fmaxf(lm, sc[m]);
  #pragma unroll
  for (int off = 32; off > 0; off >>= 1) lm = fmaxf(lm, __shfl_down(lm, off));
  if ((tid & 63) == 0) red[tid >> 6] = lm;
  __syncthreads();
  if (tid == 0) s_mx = fmaxf(fmaxf(red[0], red[1]), fmaxf(red[2], red[3]));
  __syncthreads();
  const float mx = s_mx;

  float ls = 0.f;
  for (int m = tid; m < KSEL; m += 256) {
    float pv = expf(sc[m] - mx);
    sc[m] = pv;
    ls += pv;
  }
  #pragma unroll
  for (int off = 32; off > 0; off >>= 1) ls += __shfl_down(ls, off);
  if ((tid & 63) == 0) red[tid >> 6] = ls;
  __syncthreads();
  if (tid == 0) s_sum = red[0]+red[1]+red[2]+red[3];
  __syncthreads();

  const int d = tid & 31, g = tid >> 5;
  float a = 0.f;
  for (int m = g; m < KSEL; m += 8) a += sc[m]*vb[m*256 + h*32 + d];
  part[g][d] = a;
  __syncthreads();
  if (tid < 32) {
    float s = 0.f;
    #pragma unroll
    for (int gg = 0; gg < 8; ++gg) s += part[gg][tid];
    ctx[n*256 + h*32 + tid] = s / s_sum;
  }
}

// ---------------------------------------------------------------------------
__global__ void __launch_bounds__(256) copy_kernel(
    const float4* __restrict__ src, float4* __restrict__ dst)
{
  const int i = blockIdx.x*256 + threadIdx.x;
  dst[i] = src[i];
}

__global__ void __launch_bounds__(256) scatter_kernel(
    const float* __restrict__ down, const float* __restrict__ gate,
    const int* __restrict__ sel, const float* __restrict__ att,
    float* __restrict__ out)
{
  const int n = blockIdx.x, c = threadIdx.x;
  const int l = sel[n];
  const float g = gate[l];
  const float dv = down[c*LL + l];
  out[c*LL + l] = g*att[n*256 + c] + (1.f - g)*dv;
}

// ---------------------------------------------------------------------------
extern "C" void kernel_launch(void* const* d_in, const int* in_sizes, int n_in,
                              void* d_out, int out_size, void* d_ws, size_t ws_size,
                              hipStream_t stream)
{
  (void)in_sizes; (void)n_in; (void)out_size; (void)ws_size;
  const float* down   = (const float*)d_in[0];
  const float* swinT  = (const float*)d_in[1];
  const float* wt_w   = (const float*)d_in[2];
  const float* wt_b   = (const float*)d_in[3];
  const float* ct_w   = (const float*)d_in[4];
  const float* ct_b   = (const float*)d_in[5];
  const float* up_w   = (const float*)d_in[6];
  const float* up_b   = (const float*)d_in[7];
  const float* gate_w = (const float*)d_in[8];
  const float* gate_b = (const float*)d_in[9];
  const float* ipw    = (const float*)d_in[10];
  const float* ipb    = (const float*)d_in[11];
  const float* ow     = (const float*)d_in[12];
  const float* ob     = (const float*)d_in[13];
  float* out = (float*)d_out;

  char* wsp = (char*)d_ws;
  size_t off = 0;
  auto take = [&](size_t bytes) -> void* {
    void* r = wsp + off;
    off += (bytes + 255) & ~(size_t)255;
    return r;
  };
  u16*      A     = (u16*)     take((size_t)16*258*258*32*sizeof(u16)); // 68.2 MB
  u16*      B     = (u16*)     take((size_t)16*258*258*32*sizeof(u16)); // 68.2 MB
  u16*      W3    = (u16*)     take((size_t)5898240*sizeof(u16));       // 11.8 MB
  u16*      W4    = (u16*)     take((size_t)10485760*sizeof(u16));      // 21.0 MB
  float*    gateb = (float*)   take((size_t)LL*sizeof(float));
  int*      sel   = (int*)     take(4096);
  unsigned* hist  = (unsigned*)take(4*256*sizeof(unsigned));
  int*      st    = (int*)     take(256);
  int*      cnt   = (int*)     take(256);
  int*      eqbuf = (int*)     take((size_t)EQCAP*sizeof(int));
  float*    WT    = (float*)   take((size_t)768*256*sizeof(float));
  float*    OWT   = (float*)   take((size_t)256*256*sizeof(float));
  float*    q_in  = (float*)   take((size_t)KSEL*256*sizeof(float));
  float*    kv_in = (float*)   take((size_t)KSEL*256*sizeof(float));
  float*    qkv   = (float*)   take((size_t)3*KSEL*256*sizeof(float));
  float*    ctx   = (float*)   take((size_t)KSEL*256*sizeof(float));
  float*    att   = (float*)   take((size_t)KSEL*256*sizeof(float));

  // ---- weight prep (LDS-tiled, coalesced) ----
  prep_w3_kernel<<<320, 256, 0, stream>>>(up_w, W3);
  prep_wt_kernel<<<640, 256, 0, stream>>>(ct_w, W4);

  // ---- decoder pipeline ----
  auto zbBlocks = [](int H) { return (16*(4*(H+2) - 4)*32 + 255)/256; };
  zb2_kernel<<<zbBlocks(8), 256, 0, stream>>>(A, 8);
  conv1x1_kernel<<<256, 64, 0, stream>>>(swinT, wt_w, wt_b, A);
  int r = 8;
  for (int s = 0; s < 5; ++s) {
    const int o = 2*r;
    const u16* w4s = W4 + (size_t)s*2*16*65536;
    const u16* w3s = W3 + (size_t)s*2*9*65536;
    const float* cb = ct_b + s*256;
    const float* ub = up_b + s*256;

    zb2_kernel<<<zbBlocks(o), 256, 0, stream>>>(B, o);
    const int tX = (r + 15)/16;
    if (r >= 128)
      convt_mfma<4><<<dim3(tX, r/16, 16), 256, 0, stream>>>(A, w4s, cb, B, r);
    else if (r >= 64)
      convt_mfma<2><<<dim3(tX, r/8, 16), 256, 0, stream>>>(A, w4s, cb, B, r);
    else
      convt_mfma<1><<<dim3(tX, r/4, 16), 256, 0, stream>>>(A, w4s, cb, B, r);

    zb2_kernel<<<zbBlocks(o), 256, 0, stream>>>(A, o);
    if (o >= 128)
      conv3_mfma<4><<<dim3(o/16, o/16, 4), 256, 0, stream>>>(B, w3s, ub, A, o);
    else if (o >= 64)
      conv3_mfma<2><<<dim3(o/16, o/8, 4), 256, 0, stream>>>(B, w3s, ub, A, o);
    else
      conv3_mfma<1><<<dim3(o/16, o/4, 4), 256, 0, stream>>>(B, w3s, ub, A, o);
    r = o;
  }

  // ---- gate + top-k ----
  gate_kernel<<<256, 256, 0, stream>>>(down, gate_w, gate_b, gateb);
  tk_zero<<<1, 1024, 0, stream>>>(hist, st, cnt);
  for (int p = 0; p < 4; ++p) {
    tk_hist<<<256, 256, 0, stream>>>(gateb, st, hist, p);
    tk_pick<<<1, 64, 0, stream>>>(hist, st, p);
  }
  tk_compact<<<256, 256, 0, stream>>>(gateb, st, sel, cnt, eqbuf);
  tk_fin<<<1, 1024, 0, stream>>>(sel, cnt, eqbuf);

  // ---- attention ----
  transpose_kernel<<<dim3(8, 24), 256, 0, stream>>>(ipw, WT, 768, 256);
  transpose_kernel<<<dim3(8, 8), 256, 0, stream>>>(ow, OWT, 256, 256);
  gather_kernel<<<KSEL, 256, 0, stream>>>(down, A, sel, q_in, kv_in);
  rowgemm_kernel<<<dim3(41, 3), 256, 0, stream>>>(WT, 768, q_in, kv_in, ipb, qkv, KSEL);
  attn_kernel<<<dim3(KSEL, 8), 256, 0, stream>>>(qkv, qkv + KSEL*256, qkv + 2*KSEL*256, ctx);
  rowgemm_kernel<<<dim3(41, 1), 256, 0, stream>>>(OWT, 256, ctx, ctx, ob, att, KSEL);

  // ---- output: copy down, then blend the selected pixels ----
  copy_kernel<<<16384, 256, 0, stream>>>((const float4*)down, (float4*)out);
  scatter_kernel<<<KSEL, 256, 0, stream>>>(down, gateb, sel, att, out);
}

// Round 6
// 1200.428 us; speedup vs baseline: 6.6894x; 1.1043x over previous
//
#include <hip/hip_runtime.h>

#define LL 65536      // H*W
#define KSEL 655      // top-k count
#define EQCAP 8192

typedef unsigned short u16;
typedef __attribute__((ext_vector_type(8))) short s16x8;
typedef __attribute__((ext_vector_type(4))) float f32x4;

__device__ __forceinline__ u16 f2bf(float v) {
  unsigned u = __float_as_uint(v);
  u += 0x7FFFu + ((u >> 16) & 1u);
  return (u16)(u >> 16);
}
__device__ __forceinline__ float bf2f(u16 h) {
  return __uint_as_float(((unsigned)h) << 16);
}

// ---------------------------------------------------------------------------
// Zero the borders of a padded split-activation buffer:
// layout [16 planes (g=0..7 hi, 8..15 lo)][(H+2)][(W+2)][32ci].
// ---------------------------------------------------------------------------
__global__ void zb2_kernel(u16* __restrict__ buf, int H)
{
  const int H2 = H + 2;
  const int PS = H2*H2*32;
  const int per = (4*H2 - 4)*32;
  const int tot = 16*per;
  for (int t = blockIdx.x*blockDim.x + threadIdx.x; t < tot; t += gridDim.x*blockDim.x) {
    const int pl = t / per, e = t - pl*per;
    const int pix = e >> 5, cw = e & 31;
    int y, x;
    if (pix < H2)        { y = 0;      x = pix; }
    else if (pix < 2*H2) { y = H2-1;   x = pix - H2; }
    else { int k2 = pix - 2*H2; y = 1 + (k2 >> 1); x = (k2 & 1) ? (H2-1) : 0; }
    buf[(size_t)pl*PS + ((size_t)(y*H2 + x))*32 + cw] = 0;
  }
}

// ---------------------------------------------------------------------------
// Weight prep conv3x3 (LDS-tiled transpose, coalesced both sides).
// up_w (5, co256, ci256, 3,3) fp32 ->
// W3 flat: (((((s*2+hl)*9+tap)*4+cob)*4+n)*8+ch)*512 + lane*8 + e
//   co = cob*64+n*16+(lane&15), ci = ch*32+(lane>>4)*8+e.
// ---------------------------------------------------------------------------
__global__ void __launch_bounds__(256) prep_w3_kernel(
    const float* __restrict__ up_w, u16* __restrict__ W3)
{
  const int b = blockIdx.x;
  const int cob = b & 3, ciq = (b >> 2) & 15, s = b >> 6;
  const int ci0 = ciq*16, ch = ciq >> 1, k0 = (ciq & 1)*2;
  const int tid = threadIdx.x;
  __shared__ float lds[64*145];

  for (int t = tid; t < 64*144; t += 256) {
    const int co_l = t / 144, r = t - co_l*144;
    lds[co_l*145 + r] = up_w[((size_t)((s*256 + cob*64 + co_l)*256 + ci0))*9 + r];
  }
  __syncthreads();

  for (int u = tid; u < 18432; u += 256) {
    const int within = u & 255, combo = u >> 8;
    const int n = combo & 3, c2 = combo >> 2;
    const int tap = c2 % 9, hl = c2 / 9;
    const int lane_loc = within >> 3, e = within & 7;
    const int lx = lane_loc & 15, kgl = lane_loc >> 4;
    const int co_l = n*16 + lx, ci_l = kgl*8 + e;
    const float v = lds[co_l*145 + ci_l*9 + tap];
    const u16 h = f2bf(v);
    const u16 val = hl ? f2bf(v - bf2f(h)) : h;
    const size_t addr = ((size_t)(((((s*2 + hl)*9 + tap)*4 + cob)*4 + n)*8 + ch))*512
                      + k0*128 + within;
    W3[addr] = val;
  }
}

// ---------------------------------------------------------------------------
// Weight prep convT (LDS-tiled transpose).
// ct_w (5, ci256, co256, 4,4) fp32 ->
// W4 flat: (((((s*2+hl)*16+pdt)*4+cob)*4+n)*8+ch)*512 + lane*8 + e
// pdt=p*4+dt; ky=3-py-2dy, kx=3-px-2dx.
// LDS: lds[ci_l*1089 + co_l*17 + tap].
// ---------------------------------------------------------------------------
__global__ void __launch_bounds__(256) prep_wt_kernel(
    const float* __restrict__ ct_w, u16* __restrict__ W4)
{
  const int b = blockIdx.x;
  const int cob = b & 3, ciq = (b >> 2) & 31, s = b >> 7;
  const int ci0 = ciq*8, ch = ciq >> 2, kg = ciq & 3;
  const int tid = threadIdx.x;
  __shared__ float lds[8*1089];

  for (int t = tid; t < 8192; t += 256) {
    const int ci_l = t >> 10, r = t & 1023;
    lds[ci_l*1089 + (r >> 4)*17 + (r & 15)] =
        ct_w[((size_t)((s*256 + ci0 + ci_l)*256 + cob*64))*16 + r];
  }
  __syncthreads();

  for (int u = tid; u < 16384; u += 256) {
    const int within = u & 127, combo = u >> 7;
    const int n = combo & 3, pdt = (combo >> 2) & 15, hl = combo >> 6;
    const int lx = within >> 3, e = within & 7;
    const int p = pdt >> 2, dt = pdt & 3;
    const int py = p >> 1, px = p & 1, dy = dt >> 1, dx = dt & 1;
    const int ky = 3 - py - 2*dy, kx = 3 - px - 2*dx;
    const float v = lds[e*1089 + (n*16 + lx)*17 + ky*4 + kx];
    const u16 h = f2bf(v);
    const u16 val = hl ? f2bf(v - bf2f(h)) : h;
    const size_t addr = ((size_t)(((((s*2 + hl)*16 + pdt)*4 + cob)*4 + n)*8 + ch))*512
                      + kg*128 + within;
    W4[addr] = val;
  }
}

// ---------------------------------------------------------------------------
// 1x1 conv: swinT (768,8,8) -> split activation buffer at res 8 (padded 10).
// ---------------------------------------------------------------------------
__global__ void __launch_bounds__(64) conv1x1_kernel(
    const float* __restrict__ swinT, const float* __restrict__ w,
    const float* __restrict__ b, u16* __restrict__ out)
{
  const int co = blockIdx.x, pp = threadIdx.x;
  float acc = b[co];
  for (int ci = 0; ci < 768; ++ci)
    acc += swinT[ci*64 + pp] * w[co*768 + ci];
  const int py = pp >> 3, px = pp & 7;
  const int g = co >> 5, cw = co & 31;
  const size_t o = (size_t)g*3200 + ((size_t)((py+1)*10 + px+1))*32 + cw;
  const u16 h = f2bf(acc);
  out[o] = h;
  out[o + (size_t)8*3200] = f2bf(acc - bf2f(h));
}

// ---------------------------------------------------------------------------
// conv3x3 via MFMA (split bf16), NO LDS: activation B-fragments are loaded
// directly from global (fully coalesced 1KB/wave, L1 gives dxg reuse);
// weights from global (L1-shared across the block's waves, phase-aligned by
// a bare s_barrier per ch-iter — no waitcnt drain).
// grid (H/16, H/(4*MI), 4 co-blocks of 64), block 256.
// ---------------------------------------------------------------------------
template<int MI>
__global__ void __launch_bounds__(256, 2) conv3_mfma(
    const u16* __restrict__ in, const u16* __restrict__ W,
    const float* __restrict__ bias, u16* __restrict__ out, int H)
{
  const int H2 = H + 2;
  const int PS = H2*H2*32;
  const int tid = threadIdx.x;
  const int lane = tid & 63, wv = tid >> 6;
  const int lx = lane & 15, kg = lane >> 4;
  const int X0 = blockIdx.x*16, Y0 = blockIdx.y*(4*MI);
  const int cob = blockIdx.z;
  const int yl0 = wv*MI;

  f32x4 acc[MI][4] = {};
  const u16* Wl = W + lane*8;
  const int xoff = (X0 + lx)*32 + kg*8;   // lane part of activation address

  for (int ch = 0; ch < 8; ++ch) {
    __builtin_amdgcn_s_barrier();   // phase-align waves for weight L1 reuse
    const u16* ph = in + (size_t)ch*PS;
    const u16* pl = ph + (size_t)8*PS;
    #pragma unroll
    for (int dxg = 0; dxg < 3; ++dxg) {
      s16x8 ah[MI+2], al[MI+2];
      #pragma unroll
      for (int r = 0; r < MI+2; ++r) {
        const size_t ro = (size_t)((Y0 + yl0 + r)*H2)*32 + xoff + dxg*32;
        ah[r] = *(const s16x8*)&ph[ro];
        al[r] = *(const s16x8*)&pl[ro];
      }
      #pragma unroll
      for (int dy = 0; dy < 3; ++dy) {
        const int tap = dy*3 + dxg;
        s16x8 bh[4], bl[4];
        #pragma unroll
        for (int n = 0; n < 4; ++n) {
          const int oh = (((tap*4 + cob)*4 + n)*8 + ch)*512;
          bh[n] = *(const s16x8*)&Wl[oh];
          bl[n] = *(const s16x8*)&Wl[oh + 589824];   // hl stride = 9*65536
        }
        #pragma unroll
        for (int mi = 0; mi < MI; ++mi)
          #pragma unroll
          for (int n = 0; n < 4; ++n) {
            acc[mi][n] = __builtin_amdgcn_mfma_f32_16x16x32_bf16(bh[n], ah[mi+dy], acc[mi][n], 0, 0, 0);
            acc[mi][n] = __builtin_amdgcn_mfma_f32_16x16x32_bf16(bl[n], ah[mi+dy], acc[mi][n], 0, 0, 0);
            acc[mi][n] = __builtin_amdgcn_mfma_f32_16x16x32_bf16(bh[n], al[mi+dy], acc[mi][n], 0, 0, 0);
          }
      }
    }
  }

  // D mapping: col(lane&15)=x, row(kg*4+j)=co within n-block.
  const int x = X0 + lx;
  #pragma unroll
  for (int n = 0; n < 4; ++n) {
    const int co0 = cob*64 + n*16 + kg*4;
    const float4 bv = *(const float4*)&bias[co0];
    const int g = co0 >> 5, cw = co0 & 31;
    #pragma unroll
    for (int mi = 0; mi < MI; ++mi) {
      const int y = Y0 + yl0 + mi;
      const float v0 = acc[mi][n][0] + bv.x;
      const float v1 = acc[mi][n][1] + bv.y;
      const float v2 = acc[mi][n][2] + bv.z;
      const float v3 = acc[mi][n][3] + bv.w;
      const u16 h0 = f2bf(v0), h1 = f2bf(v1), h2 = f2bf(v2), h3 = f2bf(v3);
      const size_t o = (size_t)g*PS + ((size_t)((y+1)*H2 + x+1))*32 + cw;
      *(ushort4*)&out[o] = make_ushort4(h0, h1, h2, h3);
      *(ushort4*)&out[o + (size_t)8*PS] = make_ushort4(
          f2bf(v0 - bf2f(h0)), f2bf(v1 - bf2f(h1)),
          f2bf(v2 - bf2f(h2)), f2bf(v3 - bf2f(h3)));
    }
  }
}

// ---------------------------------------------------------------------------
// ConvTranspose2d k4 s2 p1 + ReLU via MFMA (split bf16), parity-decomposed,
// NO LDS (same global-direct scheme as conv3).
// grid (ceil(Hin/16), Hin/(4*MI), 16: z = parity*4 + co-block), block 256.
// Note: for Hin=8 the x-columns overshoot the padded row; the reads stay
// inside the (huge) activation allocation and the results are discarded by
// the xi<Hin store guard.
// ---------------------------------------------------------------------------
template<int MI>
__global__ void __launch_bounds__(256, 2) convt_mfma(
    const u16* __restrict__ in, const u16* __restrict__ W,
    const float* __restrict__ bias, u16* __restrict__ out, int Hin)
{
  const int Hout = Hin*2;
  const int H2i = Hin + 2, H2o = Hout + 2;
  const int PSi = H2i*H2i*32, PSo = H2o*H2o*32;
  const int tid = threadIdx.x;
  const int lane = tid & 63, wv = tid >> 6;
  const int lx = lane & 15, kg = lane >> 4;
  const int X0 = blockIdx.x*16, Y0 = blockIdx.y*(4*MI);
  const int p = blockIdx.z >> 2, cob = blockIdx.z & 3;
  const int py = p >> 1, px = p & 1;
  const int yl0 = wv*MI;

  f32x4 acc[MI][4] = {};
  const u16* Wl = W + lane*8;
  const int xoff = (X0 + px + lx)*32 + kg*8;

  for (int ch = 0; ch < 8; ++ch) {
    __builtin_amdgcn_s_barrier();
    const u16* ph = in + (size_t)ch*PSi;
    const u16* pl = ph + (size_t)8*PSi;
    #pragma unroll
    for (int dxg = 0; dxg < 2; ++dxg) {
      s16x8 ah[MI+1], al[MI+1];
      #pragma unroll
      for (int r = 0; r < MI+1; ++r) {
        const size_t ro = (size_t)((Y0 + yl0 + py + r)*H2i)*32 + xoff + dxg*32;
        ah[r] = *(const s16x8*)&ph[ro];
        al[r] = *(const s16x8*)&pl[ro];
      }
      #pragma unroll
      for (int dy = 0; dy < 2; ++dy) {
        const int pdt = p*4 + dy*2 + dxg;
        s16x8 bh[4], bl[4];
        #pragma unroll
        for (int n = 0; n < 4; ++n) {
          const int oh = (((pdt*4 + cob)*4 + n)*8 + ch)*512;
          bh[n] = *(const s16x8*)&Wl[oh];
          bl[n] = *(const s16x8*)&Wl[oh + 1048576];  // hl stride = 16*65536
        }
        #pragma unroll
        for (int mi = 0; mi < MI; ++mi)
          #pragma unroll
          for (int n = 0; n < 4; ++n) {
            acc[mi][n] = __builtin_amdgcn_mfma_f32_16x16x32_bf16(bh[n], ah[mi+dy], acc[mi][n], 0, 0, 0);
            acc[mi][n] = __builtin_amdgcn_mfma_f32_16x16x32_bf16(bl[n], ah[mi+dy], acc[mi][n], 0, 0, 0);
            acc[mi][n] = __builtin_amdgcn_mfma_f32_16x16x32_bf16(bh[n], al[mi+dy], acc[mi][n], 0, 0, 0);
          }
      }
    }
  }

  const int xi = X0 + lx;
  if (xi < Hin) {
    const int X = 2*xi + px;
    #pragma unroll
    for (int n = 0; n < 4; ++n) {
      const int co0 = cob*64 + n*16 + kg*4;
      const float4 bv = *(const float4*)&bias[co0];
      const int g = co0 >> 5, cw = co0 & 31;
      #pragma unroll
      for (int mi = 0; mi < MI; ++mi) {
        const int Y = 2*(Y0 + yl0 + mi) + py;
        const float v0 = fmaxf(acc[mi][n][0] + bv.x, 0.f);
        const float v1 = fmaxf(acc[mi][n][1] + bv.y, 0.f);
        const float v2 = fmaxf(acc[mi][n][2] + bv.z, 0.f);
        const float v3 = fmaxf(acc[mi][n][3] + bv.w, 0.f);
        const u16 h0 = f2bf(v0), h1 = f2bf(v1), h2 = f2bf(v2), h3 = f2bf(v3);
        const size_t o = (size_t)g*PSo + ((size_t)((Y+1)*H2o + X+1))*32 + cw;
        *(ushort4*)&out[o] = make_ushort4(h0, h1, h2, h3);
        *(ushort4*)&out[o + (size_t)8*PSo] = make_ushort4(
            f2bf(v0 - bf2f(h0)), f2bf(v1 - bf2f(h1)),
            f2bf(v2 - bf2f(h2)), f2bf(v3 - bf2f(h3)));
      }
    }
  }
}

// ---------------------------------------------------------------------------
// gate[l] = sigmoid(sum_c down[c*L+l]*gw[c] + gb); block 0 also zeroes the
// top-k state (fused tk_zero).
// ---------------------------------------------------------------------------
__global__ void __launch_bounds__(256) gate_kernel(
    const float* __restrict__ down, const float* __restrict__ gw,
    const float* __restrict__ gb, float* __restrict__ gate,
    unsigned* __restrict__ hist, int* __restrict__ st, int* __restrict__ cnt)
{
  if (blockIdx.x == 0) {
    const int t = threadIdx.x;
    #pragma unroll
    for (int j = 0; j < 4; ++j) hist[j*256 + t] = 0;
    if (t == 0) { st[0] = 0; st[1] = KSEL; cnt[0] = 0; cnt[1] = 0; }
  }
  const int l = blockIdx.x*256 + threadIdx.x;
  float a0 = 0.f, a1 = 0.f, a2 = 0.f, a3 = 0.f;
  for (int c = 0; c < 256; c += 4) {
    a0 += down[(c+0)*LL + l] * gw[c+0];
    a1 += down[(c+1)*LL + l] * gw[c+1];
    a2 += down[(c+2)*LL + l] * gw[c+2];
    a3 += down[(c+3)*LL + l] * gw[c+3];
  }
  const float a = (a0+a1) + (a2+a3) + gb[0];
  gate[l] = 1.f / (1.f + expf(-a));
}

// ---------------------------------------------------------------------------
// Grid-wide exact top-K radix select (set semantics; ties -> lowest index).
// ---------------------------------------------------------------------------
__global__ void __launch_bounds__(256) tk_hist(
    const float* __restrict__ gate, const int* __restrict__ st,
    unsigned* __restrict__ hist, int pass)
{
  __shared__ unsigned lh[256];
  lh[threadIdx.x] = 0;
  __syncthreads();
  const unsigned pref = (unsigned)st[0];
  const int shift = 24 - 8*pass;
  for (int i = blockIdx.x*256 + threadIdx.x; i < LL; i += gridDim.x*256) {
    const unsigned u = __float_as_uint(gate[i]);
    const bool ok = (pass == 0) || ((u >> (shift + 8)) == pref);
    if (ok) atomicAdd(&lh[(u >> shift) & 255u], 1u);
  }
  __syncthreads();
  const unsigned c = lh[threadIdx.x];
  if (c) atomicAdd(&hist[pass*256 + threadIdx.x], c);
}

__global__ void tk_pick(const unsigned* __restrict__ hist, int* __restrict__ st, int pass)
{
  if (threadIdx.x != 0) return;
  const unsigned pref = (unsigned)st[0];
  int kk = st[1];
  const unsigned* h = hist + pass*256;
  int cum = 0, b = 255;
  for (; b >= 0; --b) {
    const int c = (int)h[b];
    if (cum + c >= kk) break;
    cum += c;
  }
  if (b < 0) b = 0;
  st[0] = (int)((pref << 8) | (unsigned)b);
  st[1] = kk - cum;
}

__global__ void __launch_bounds__(256) tk_compact(
    const float* __restrict__ gate, const int* __restrict__ st,
    int* __restrict__ sel, int* __restrict__ cnt, int* __restrict__ eqbuf)
{
  const unsigned T = (unsigned)st[0];
  for (int i = blockIdx.x*256 + threadIdx.x; i < LL; i += gridDim.x*256) {
    const unsigned u = __float_as_uint(gate[i]);
    if (u > T) {
      const int p = atomicAdd(&cnt[0], 1);
      sel[p] = i;
    } else if (u == T) {
      const int p = atomicAdd(&cnt[1], 1);
      if (p < EQCAP) eqbuf[p] = i;
    }
  }
}

__global__ void __launch_bounds__(1024) tk_fin(
    int* __restrict__ sel, const int* __restrict__ cnt, const int* __restrict__ eqbuf)
{
  const int g = cnt[0];
  const int need = KSEL - g;
  int M = cnt[1]; if (M > EQCAP) M = EQCAP;
  for (int x = threadIdx.x; x < M; x += 1024) {
    const int v = eqbuf[x];
    int rank = 0;
    for (int j = 0; j < M; ++j) rank += (eqbuf[j] < v);
    if (rank < need) sel[g + rank] = v;
  }
}

// ---------------------------------------------------------------------------
__global__ void __launch_bounds__(256) transpose_kernel(
    const float* __restrict__ in, float* __restrict__ out, int R, int Ck)
{
  __shared__ float t[32][33];
  const int bx = blockIdx.x*32, by = blockIdx.y*32;
  const int x = threadIdx.x & 31, y4 = threadIdx.x >> 5;
  #pragma unroll
  for (int i = 0; i < 4; ++i) {
    int r = by + y4 + i*8, c = bx + x;
    t[y4 + i*8][x] = (r < R && c < Ck) ? in[r*Ck + c] : 0.f;
  }
  __syncthreads();
  #pragma unroll
  for (int i = 0; i < 4; ++i) {
    int c = bx + y4 + i*8, r = by + x;
    if (c < Ck && r < R) out[c*R + r] = t[x][y4 + i*8];
  }
}

// ---------------------------------------------------------------------------
// Gather: q from down (C,L); kv from final split buffer (res 256, padded 258).
// ---------------------------------------------------------------------------
__global__ void __launch_bounds__(256) gather_kernel(
    const float* __restrict__ down, const u16* __restrict__ xf,
    const int* __restrict__ sel, float* __restrict__ q_in, float* __restrict__ kv_in)
{
  const int n = blockIdx.x, c = threadIdx.x;
  const int l = sel[n];
  q_in[n*256 + c] = down[c*LL + l];
  const int pr = (l >> 8) + 1, pc = (l & 255) + 1;
  const size_t PS = (size_t)258*258*32;
  const size_t o = (size_t)(c >> 5)*PS + ((size_t)(pr*258 + pc))*32 + (c & 31);
  kv_in[n*256 + c] = bf2f(xf[o]) + bf2f(xf[o + (size_t)8*PS]);
}

// ---------------------------------------------------------------------------
__global__ void __launch_bounds__(256) rowgemm_kernel(
    const float* __restrict__ WT, int wld,
    const float* __restrict__ srcA, const float* __restrict__ srcB,
    const float* __restrict__ bias, float* __restrict__ out, int N)
{
  const int g = blockIdx.y;
  const int tid = threadIdx.x;
  const int co = g*256 + tid;
  const float* src = (g == 0) ? srcA : srcB;
  float* outg = out + (size_t)g*(KSEL*256);
  __shared__ float Bl[16][256];
  const int n0 = blockIdx.x*16;
  #pragma unroll
  for (int j = 0; j < 16; ++j) {
    int n = n0 + j;
    Bl[j][tid] = (n < N) ? src[n*256 + tid] : 0.f;
  }
  __syncthreads();
  float acc[16];
  const float bv = bias[co];
  #pragma unroll
  for (int j = 0; j < 16; ++j) acc[j] = bv;
  #pragma unroll 4
  for (int ci = 0; ci < 256; ++ci) {
    const float w = WT[ci*wld + co];
    #pragma unroll
    for (int j = 0; j < 16; ++j) acc[j] += Bl[j][ci]*w;
  }
  #pragma unroll
  for (int j = 0; j < 16; ++j) {
    int n = n0 + j;
    if (n < N) outg[n*256 + tid] = acc[j];
  }
}

// ---------------------------------------------------------------------------
__global__ void __launch_bounds__(256) attn_kernel(
    const float* __restrict__ qb, const float* __restrict__ kb,
    const float* __restrict__ vb, float* __restrict__ ctx)
{
  const int n = blockIdx.x, h = blockIdx.y;
  const int tid = threadIdx.x;
  __shared__ float sc[KSEL];
  __shared__ float qv[32];
  __shared__ float red[4];
  __shared__ float part[8][32];
  __shared__ float s_mx, s_sum;

  if (tid < 32) qv[tid] = qb[n*256 + h*32 + tid];
  __syncthreads();

  const float scale = 0.17677669529663687f;
  for (int m = tid; m < KSEL; m += 256) {
    const float* kr = kb + m*256 + h*32;
    float s = 0.f;
    #pragma unroll
    for (int d = 0; d < 32; ++d) s += qv[d]*kr[d];
    sc[m] = s*scale;
  }
  __syncthreads();

  float lm = -1e30f;
  for (int m = tid; m < KSEL; m += 256) lm = fmaxf(lm, sc[m]);
  #pragma unroll
  for (int off = 32; off > 0; off >>= 1) lm = fmaxf(lm, __shfl_down(lm, off));
  if ((tid & 63) == 0) red[tid >> 6] = lm;
  __syncthreads();
  if (tid == 0) s_mx = fmaxf(fmaxf(red[0], red[1]), fmaxf(red[2], red[3]));
  __syncthreads();
  const float mx = s_mx;

  float ls = 0.f;
  for (int m = tid; m < KSEL; m += 256) {
    float pv = expf(sc[m] - mx);
    sc[m] = pv;
    ls += pv;
  }
  #pragma unroll
  for (int off = 32; off > 0; off >>= 1) ls += __shfl_down(ls, off);
  if ((tid & 63) == 0) red[tid >> 6] = ls;
  __syncthreads();
  if (tid == 0) s_sum = red[0]+red[1]+red[2]+red[3];
  __syncthreads();

  const int d = tid & 31, g = tid >> 5;
  float a = 0.f;
  for (int m = g; m < KSEL; m += 8) a += sc[m]*vb[m*256 + h*32 + d];
  part[g][d] = a;
  __syncthreads();
  if (tid < 32) {
    float s = 0.f;
    #pragma unroll
    for (int gg = 0; gg < 8; ++gg) s += part[gg][tid];
    ctx[n*256 + h*32 + tid] = s / s_sum;
  }
}

// ---------------------------------------------------------------------------
__global__ void __launch_bounds__(256) copy_kernel(
    const float4* __restrict__ src, float4* __restrict__ dst)
{
  const int i = blockIdx.x*256 + threadIdx.x;
  dst[i] = src[i];
}

__global__ void __launch_bounds__(256) scatter_kernel(
    const float* __restrict__ down, const float* __restrict__ gate,
    const int* __restrict__ sel, const float* __restrict__ att,
    float* __restrict__ out)
{
  const int n = blockIdx.x, c = threadIdx.x;
  const int l = sel[n];
  const float g = gate[l];
  const float dv = down[c*LL + l];
  out[c*LL + l] = g*att[n*256 + c] + (1.f - g)*dv;
}

// ---------------------------------------------------------------------------
extern "C" void kernel_launch(void* const* d_in, const int* in_sizes, int n_in,
                              void* d_out, int out_size, void* d_ws, size_t ws_size,
                              hipStream_t stream)
{
  (void)in_sizes; (void)n_in; (void)out_size; (void)ws_size;
  const float* down   = (const float*)d_in[0];
  const float* swinT  = (const float*)d_in[1];
  const float* wt_w   = (const float*)d_in[2];
  const float* wt_b   = (const float*)d_in[3];
  const float* ct_w   = (const float*)d_in[4];
  const float* ct_b   = (const float*)d_in[5];
  const float* up_w   = (const float*)d_in[6];
  const float* up_b   = (const float*)d_in[7];
  const float* gate_w = (const float*)d_in[8];
  const float* gate_b = (const float*)d_in[9];
  const float* ipw    = (const float*)d_in[10];
  const float* ipb    = (const float*)d_in[11];
  const float* ow     = (const float*)d_in[12];
  const float* ob     = (const float*)d_in[13];
  float* out = (float*)d_out;

  char* wsp = (char*)d_ws;
  size_t off = 0;
  auto take = [&](size_t bytes) -> void* {
    void* r = wsp + off;
    off += (bytes + 255) & ~(size_t)255;
    return r;
  };
  u16*      A     = (u16*)     take((size_t)16*258*258*32*sizeof(u16)); // 68.2 MB
  u16*      B     = (u16*)     take((size_t)16*258*258*32*sizeof(u16)); // 68.2 MB
  u16*      W3    = (u16*)     take((size_t)5898240*sizeof(u16));       // 11.8 MB
  u16*      W4    = (u16*)     take((size_t)10485760*sizeof(u16));      // 21.0 MB
  float*    gateb = (float*)   take((size_t)LL*sizeof(float));
  int*      sel   = (int*)     take(4096);
  unsigned* hist  = (unsigned*)take(4*256*sizeof(unsigned));
  int*      st    = (int*)     take(256);
  int*      cnt   = (int*)     take(256);
  int*      eqbuf = (int*)     take((size_t)EQCAP*sizeof(int));
  float*    WT    = (float*)   take((size_t)768*256*sizeof(float));
  float*    OWT   = (float*)   take((size_t)256*256*sizeof(float));
  float*    q_in  = (float*)   take((size_t)KSEL*256*sizeof(float));
  float*    kv_in = (float*)   take((size_t)KSEL*256*sizeof(float));
  float*    qkv   = (float*)   take((size_t)3*KSEL*256*sizeof(float));
  float*    ctx   = (float*)   take((size_t)KSEL*256*sizeof(float));
  float*    att   = (float*)   take((size_t)KSEL*256*sizeof(float));

  // ---- weight prep (LDS-tiled, coalesced) ----
  prep_w3_kernel<<<320, 256, 0, stream>>>(up_w, W3);
  prep_wt_kernel<<<640, 256, 0, stream>>>(ct_w, W4);

  // ---- decoder pipeline ----
  auto zbBlocks = [](int H) { return (16*(4*(H+2) - 4)*32 + 255)/256; };
  zb2_kernel<<<zbBlocks(8), 256, 0, stream>>>(A, 8);
  conv1x1_kernel<<<256, 64, 0, stream>>>(swinT, wt_w, wt_b, A);
  int r = 8;
  for (int s = 0; s < 5; ++s) {
    const int o = 2*r;
    const u16* w4s = W4 + (size_t)s*2*16*65536;
    const u16* w3s = W3 + (size_t)s*2*9*65536;
    const float* cb = ct_b + s*256;
    const float* ub = up_b + s*256;

    zb2_kernel<<<zbBlocks(o), 256, 0, stream>>>(B, o);
    const int tX = (r + 15)/16;
    if (r >= 128)
      convt_mfma<4><<<dim3(tX, r/16, 16), 256, 0, stream>>>(A, w4s, cb, B, r);
    else if (r >= 64)
      convt_mfma<2><<<dim3(tX, r/8, 16), 256, 0, stream>>>(A, w4s, cb, B, r);
    else
      convt_mfma<1><<<dim3(tX, r/4, 16), 256, 0, stream>>>(A, w4s, cb, B, r);

    zb2_kernel<<<zbBlocks(o), 256, 0, stream>>>(A, o);
    if (o >= 128)
      conv3_mfma<4><<<dim3(o/16, o/16, 4), 256, 0, stream>>>(B, w3s, ub, A, o);
    else if (o >= 64)
      conv3_mfma<2><<<dim3(o/16, o/8, 4), 256, 0, stream>>>(B, w3s, ub, A, o);
    else
      conv3_mfma<1><<<dim3(o/16, o/4, 4), 256, 0, stream>>>(B, w3s, ub, A, o);
    r = o;
  }

  // ---- gate + top-k ----
  gate_kernel<<<256, 256, 0, stream>>>(down, gate_w, gate_b, gateb, hist, st, cnt);
  for (int p = 0; p < 4; ++p) {
    tk_hist<<<256, 256, 0, stream>>>(gateb, st, hist, p);
    tk_pick<<<1, 64, 0, stream>>>(hist, st, p);
  }
  tk_compact<<<256, 256, 0, stream>>>(gateb, st, sel, cnt, eqbuf);
  tk_fin<<<1, 1024, 0, stream>>>(sel, cnt, eqbuf);

  // ---- attention ----
  transpose_kernel<<<dim3(8, 24), 256, 0, stream>>>(ipw, WT, 768, 256);
  transpose_kernel<<<dim3(8, 8), 256, 0, stream>>>(ow, OWT, 256, 256);
  gather_kernel<<<KSEL, 256, 0, stream>>>(down, A, sel, q_in, kv_in);
  rowgemm_kernel<<<dim3(41, 3), 256, 0, stream>>>(WT, 768, q_in, kv_in, ipb, qkv, KSEL);
  attn_kernel<<<dim3(KSEL, 8), 256, 0, stream>>>(qkv, qkv + KSEL*256, qkv + 2*KSEL*256, ctx);
  rowgemm_kernel<<<dim3(41, 1), 256, 0, stream>>>(OWT, 256, ctx, ctx, ob, att, KSEL);

  // ---- output: copy down, then blend the selected pixels ----
  copy_kernel<<<16384, 256, 0, stream>>>((const float4*)down, (float4*)out);
  scatter_kernel<<<KSEL, 256, 0, stream>>>(down, gateb, sel, att, out);
}